// Round 2
// baseline (993.095 us; speedup 1.0000x reference)
//
#include <hip/hip_runtime.h>
#include <cstdint>
#include <cstddef>

#define D_MODEL  256
#define D_FLOW   128
#define D_FFN    1024
#define N_HEADS  8
#define N_LEVELS 3
#define N_POINTS 4
#define D_HEAD   32
#define LQ       16384
#define LENIN    21504
#define NB       2

// ---------------------------------------------------------------------------
// Generic fp32 tiled GEMM: C[M,N] = A[M,K] @ B[K,N] + bias[N]
// optional ReLU, optional residual add (resid may alias C elementwise).
// BM=BN=64, BK=16, 256 threads, 4x4 microtile per thread.
// Requires: M % 64 == 0, K % 16 == 0, N % 4 == 0 (N may be non-mult-of-64).
// ---------------------------------------------------------------------------
template<bool RELU, bool RESID>
__global__ __launch_bounds__(256)
void gemm_k(const float* __restrict__ A, const float* __restrict__ B,
            const float* __restrict__ bias, const float* resid,
            float* C, int M, int N, int K)
{
    __shared__ float As[16][68];   // [k][m]; row stride 272B is 16B-aligned
    __shared__ float Bs[16][64];   // [k][n]

    const int tid = threadIdx.x;
    const int bm  = blockIdx.y * 64;
    const int bn  = blockIdx.x * 64;
    const int tx  = tid & 15;        // output col group
    const int ty  = tid >> 4;        // output row group
    const int aRow = tid >> 2;       // 0..63
    const int aCol = (tid & 3) << 2; // 0,4,8,12
    const int bRow = tid >> 4;       // 0..15
    const int bCol = (tid & 15) << 2;// 0..60

    float acc[4][4] = {};

    for (int k0 = 0; k0 < K; k0 += 16) {
        // Stage A tile (transposed into LDS) — M,K multiples guarantee in-bounds
        float4 av = *(const float4*)(A + (size_t)(bm + aRow) * K + k0 + aCol);
        // Stage B tile, guard N
        float4 bv = make_float4(0.f, 0.f, 0.f, 0.f);
        if (bn + bCol < N)
            bv = *(const float4*)(B + (size_t)(k0 + bRow) * N + bn + bCol);

        As[aCol + 0][aRow] = av.x;
        As[aCol + 1][aRow] = av.y;
        As[aCol + 2][aRow] = av.z;
        As[aCol + 3][aRow] = av.w;
        *(float4*)&Bs[bRow][bCol] = bv;
        __syncthreads();

#pragma unroll
        for (int kk = 0; kk < 16; ++kk) {
            float4 a = *(const float4*)&As[kk][ty * 4];
            float4 b = *(const float4*)&Bs[kk][tx * 4];
            acc[0][0] = fmaf(a.x, b.x, acc[0][0]);
            acc[0][1] = fmaf(a.x, b.y, acc[0][1]);
            acc[0][2] = fmaf(a.x, b.z, acc[0][2]);
            acc[0][3] = fmaf(a.x, b.w, acc[0][3]);
            acc[1][0] = fmaf(a.y, b.x, acc[1][0]);
            acc[1][1] = fmaf(a.y, b.y, acc[1][1]);
            acc[1][2] = fmaf(a.y, b.z, acc[1][2]);
            acc[1][3] = fmaf(a.y, b.w, acc[1][3]);
            acc[2][0] = fmaf(a.z, b.x, acc[2][0]);
            acc[2][1] = fmaf(a.z, b.y, acc[2][1]);
            acc[2][2] = fmaf(a.z, b.z, acc[2][2]);
            acc[2][3] = fmaf(a.z, b.w, acc[2][3]);
            acc[3][0] = fmaf(a.w, b.x, acc[3][0]);
            acc[3][1] = fmaf(a.w, b.y, acc[3][1]);
            acc[3][2] = fmaf(a.w, b.z, acc[3][2]);
            acc[3][3] = fmaf(a.w, b.w, acc[3][3]);
        }
        __syncthreads();
    }

#pragma unroll
    for (int i = 0; i < 4; ++i) {
        const int row = bm + ty * 4 + i;
#pragma unroll
        for (int j = 0; j < 4; ++j) {
            const int col = bn + tx * 4 + j;
            if (col < N) {
                const size_t idx = (size_t)row * N + col;
                float c = acc[i][j] + bias[col];
                if (RELU) c = fmaxf(c, 0.f);
                if (RESID) c += resid[idx];
                C[idx] = c;
            }
        }
    }
}

// ---------------------------------------------------------------------------
// Fused softmax + multi-scale deformable bilinear sampling.
// One block per (n, q). threadIdx.x = channel d (0..31), threadIdx.y = head.
// value: [N, LENIN, 256]; offraw: [N*LQ, 192]; attnraw: [N*LQ, 96]
// acc out: [N*LQ, 256]
// ---------------------------------------------------------------------------
__global__ __launch_bounds__(256)
void sample_k(const float* __restrict__ value, const float* __restrict__ offraw,
              const float* __restrict__ attnraw, float* __restrict__ acc)
{
    __shared__ float sOff[N_HEADS * N_LEVELS * N_POINTS * 2]; // 192
    __shared__ float sAttn[N_HEADS][N_LEVELS * N_POINTS];     // 8 x 12 = 96

    const int bq = blockIdx.x;          // n*LQ + q
    const int n  = bq >> 14;            // / 16384
    const int q  = bq & 16383;
    const int d  = threadIdx.x;         // 0..31
    const int h  = threadIdx.y;         // 0..7
    const int tid = h * 32 + d;

    if (tid < 192) sOff[tid] = offraw[(size_t)bq * 192 + tid];
    // FIX (round 1): previous condition covered only 64 of 96 attn elements,
    // leaving sAttn for heads >=5 uninitialized. Threads 160..255 cover all 96.
    if (tid >= 160) {
        const int j = tid - 160;        // 0..95
        sAttn[j / 12][j % 12] = attnraw[(size_t)bq * 96 + j];
    }
    __syncthreads();

    if (d == 0) {   // 8 threads: one softmax(12) per head
        float m = sAttn[h][0];
#pragma unroll
        for (int j = 1; j < 12; ++j) m = fmaxf(m, sAttn[h][j]);
        float s = 0.f;
#pragma unroll
        for (int j = 0; j < 12; ++j) {
            const float e = __expf(sAttn[h][j] - m);
            sAttn[h][j] = e;
            s += e;
        }
        const float inv = 1.f / s;
#pragma unroll
        for (int j = 0; j < 12; ++j) sAttn[h][j] *= inv;
    }
    __syncthreads();

    // reference point on level-0 grid (128x128), align_corners=False
    const float refx = ((q & 127) + 0.5f) * (1.f / 128.f);
    const float refy = ((q >> 7) + 0.5f) * (1.f / 128.f);

    const int HW[3]  = {128, 64, 32};
    const int LSI[3] = {0, 16384, 20480};

    float a = 0.f;
    const float* vbase = value + (size_t)n * LENIN * D_MODEL + h * D_HEAD + d;

#pragma unroll
    for (int l = 0; l < N_LEVELS; ++l) {
        const int   W  = HW[l];
        const float fW = (float)W;
        const float* vlev = vbase + (size_t)LSI[l] * D_MODEL;
#pragma unroll
        for (int p = 0; p < N_POINTS; ++p) {
            const int ob = (h * N_LEVELS + l) * (N_POINTS * 2) + p * 2;
            const float aw = sAttn[h][l * 4 + p];
            const float locx = refx + sOff[ob + 0] / fW;
            const float locy = refy + sOff[ob + 1] / fW;   // square levels: H==W
            const float x = locx * fW - 0.5f;
            const float y = locy * fW - 0.5f;
            const float x0 = floorf(x), y0 = floorf(y);
            const float dx = x - x0,   dy = y - y0;
#pragma unroll
            for (int cy = 0; cy < 2; ++cy) {
#pragma unroll
                for (int cx = 0; cx < 2; ++cx) {
                    const float ix = x0 + (float)cx;
                    const float iy = y0 + (float)cy;
                    const float w  = (cx ? dx : 1.f - dx) * (cy ? dy : 1.f - dy);
                    const bool valid = (ix >= 0.f) && (ix <= fW - 1.f) &&
                                       (iy >= 0.f) && (iy <= fW - 1.f);
                    const int xi = min(max((int)ix, 0), W - 1);
                    const int yi = min(max((int)iy, 0), W - 1);
                    const float g = vlev[(size_t)(yi * W + xi) * D_MODEL];
                    a = fmaf(valid ? w * aw : 0.f, g, a);
                }
            }
        }
    }
    acc[(size_t)bq * D_MODEL + h * D_HEAD + d] = a;
}

// ---------------------------------------------------------------------------
// LayerNorm over 256: one wave per row (4 rows / 256-thread block).
// ---------------------------------------------------------------------------
__global__ __launch_bounds__(256)
void ln_k(const float* __restrict__ x, const float* __restrict__ gamma,
          const float* __restrict__ beta, float* __restrict__ out)
{
    const int wave = threadIdx.x >> 6;
    const int lane = threadIdx.x & 63;
    const size_t row = (size_t)blockIdx.x * 4 + wave;

    const float4 v = *(const float4*)(x + row * 256 + lane * 4);
    float s  = v.x + v.y + v.z + v.w;
    float s2 = v.x * v.x + v.y * v.y + v.z * v.z + v.w * v.w;
#pragma unroll
    for (int off = 32; off > 0; off >>= 1) {
        s  += __shfl_xor(s, off);
        s2 += __shfl_xor(s2, off);
    }
    const float mu  = s * (1.f / 256.f);
    const float var = s2 * (1.f / 256.f) - mu * mu;
    const float r   = rsqrtf(var + 1e-5f);

    const float4 g = *(const float4*)(gamma + lane * 4);
    const float4 b = *(const float4*)(beta + lane * 4);
    float4 o;
    o.x = (v.x - mu) * r * g.x + b.x;
    o.y = (v.y - mu) * r * g.y + b.y;
    o.z = (v.z - mu) * r * g.z + b.z;
    o.w = (v.w - mu) * r * g.w + b.w;
    *(float4*)(out + row * 256 + lane * 4) = o;
}

// ---------------------------------------------------------------------------
extern "C" void kernel_launch(void* const* d_in, const int* in_sizes, int n_in,
                              void* d_out, int out_size, void* d_ws, size_t ws_size,
                              hipStream_t stream)
{
    const float* src     = (const float*)d_in[0];
    const float* flow    = (const float*)d_in[1];
    // d_in[2] spatial_shapes, d_in[3] level_start_index: compile-time constants here
    const float* w_value = (const float*)d_in[4];
    const float* b_value = (const float*)d_in[5];
    const float* w_off   = (const float*)d_in[6];
    const float* b_off   = (const float*)d_in[7];
    const float* w_attn  = (const float*)d_in[8];
    const float* b_attn  = (const float*)d_in[9];
    const float* w_out   = (const float*)d_in[10];
    const float* b_out   = (const float*)d_in[11];
    const float* gamma   = (const float*)d_in[12];
    const float* beta    = (const float*)d_in[13];
    const float* w1      = (const float*)d_in[14];
    const float* b1      = (const float*)d_in[15];
    const float* w2      = (const float*)d_in[16];
    const float* b2      = (const float*)d_in[17];
    float* out = (float*)d_out;
    float* ws  = (float*)d_ws;

    // Workspace layout (floats), with lifetime-based aliasing:
    //   [0 .. 33,554,432)  ffn1 region (written at step 7)
    //       value   @ 0           (11,010,048)  dead after step 4
    //       offraw  @ 11,010,048  ( 6,291,456)  dead after step 4
    //       attnraw @ 17,301,504  ( 3,145,728)  dead after step 4
    //   [33,554,432 .. 41,943,040)  acc (steps 4-5), then ln (steps 6-7)
    float* ffn1    = ws;
    float* value   = ws;
    float* offraw  = ws + 11010048;
    float* attnraw = ws + 17301504;
    float* accb    = ws + 33554432;
    float* lnb     = accb;

    const int Mq = NB * LQ;     // 32768
    const int Mv = NB * LENIN;  // 43008

    // 1. value = src @ w_value + b_value          [43008 x 256]
    gemm_k<false, false><<<dim3(D_MODEL / 64, Mv / 64), 256, 0, stream>>>(
        src, w_value, b_value, nullptr, value, Mv, D_MODEL, D_MODEL);

    // 2. offraw = flow @ w_off + b_off            [32768 x 192]
    gemm_k<false, false><<<dim3(192 / 64, Mq / 64), 256, 0, stream>>>(
        flow, w_off, b_off, nullptr, offraw, Mq, 192, D_FLOW);

    // 3. attnraw = flow @ w_attn + b_attn         [32768 x 96]
    gemm_k<false, false><<<dim3(2, Mq / 64), 256, 0, stream>>>(
        flow, w_attn, b_attn, nullptr, attnraw, Mq, 96, D_FLOW);

    // 4. deformable sampling (fused softmax)      [32768 x 256]
    sample_k<<<Mq, dim3(32, 8), 0, stream>>>(value, offraw, attnraw, accb);

    // 5. x = acc @ w_out + b_out  -> d_out        [32768 x 256]
    gemm_k<false, false><<<dim3(D_MODEL / 64, Mq / 64), 256, 0, stream>>>(
        accb, w_out, b_out, nullptr, out, Mq, D_MODEL, D_MODEL);

    // 6. ln = LayerNorm(x)
    ln_k<<<Mq / 4, 256, 0, stream>>>(out, gamma, beta, lnb);

    // 7. ffn1 = relu(ln @ w1 + b1)                [32768 x 1024]
    gemm_k<true, false><<<dim3(D_FFN / 64, Mq / 64), 256, 0, stream>>>(
        lnb, w1, b1, nullptr, ffn1, Mq, D_FFN, D_MODEL);

    // 8. out = x + ffn1 @ w2 + b2                 [32768 x 256]
    gemm_k<false, true><<<dim3(D_MODEL / 64, Mq / 64), 256, 0, stream>>>(
        ffn1, w2, b2, out, out, Mq, D_MODEL, D_FFN);
}

// Round 3
// 501.830 us; speedup vs baseline: 1.9789x; 1.9789x over previous
//
#include <hip/hip_runtime.h>
#include <cstdint>
#include <cstddef>

#define D_MODEL  256
#define D_FLOW   128
#define D_FFN    1024
#define N_HEADS  8
#define N_LEVELS 3
#define N_POINTS 4
#define D_HEAD   32
#define LQ       16384
#define LENIN    21504
#define NB       2

typedef unsigned short ushort;
typedef __attribute__((ext_vector_type(8))) short bf16x8;   // 8 bf16 in 4 VGPRs
typedef __attribute__((ext_vector_type(4))) float f32x4;

__device__ __forceinline__ ushort f2b(float f) {            // fp32 -> bf16 RNE
    uint32_t u = __float_as_uint(f);
    uint32_t r = (u + 0x7fffu + ((u >> 16) & 1u)) >> 16;
    return (ushort)r;
}

// ---------------------------------------------------------------------------
// bf16 MFMA GEMM: C[M,N] = A[M,K] @ B^T[N,K] + bias[N]  (B passed pre-transposed)
// BM=BN=128, BK=32. 256 threads = 4 waves in 2x2; each wave: 4x4 tiles of
// 16x16x32 MFMA. LDS rows padded 32->40 bf16 (80B stride -> 2-way max, free).
// Requires M%128==0, N%128==0, K%32==0.
// A-frag: m=lane&15, k=quad*8+j. B-frag: n=lane&15, k=quad*8+j.
// C/D:    col=lane&15, row=quad*4+reg.   [per verified gfx950 layouts]
// ---------------------------------------------------------------------------
template<bool RELU, bool RESID, bool OUT_BF16>
__global__ __launch_bounds__(256)
void mfma_gemm(const ushort* __restrict__ A, const ushort* __restrict__ Bt,
               const float* __restrict__ bias, const float* __restrict__ resid,
               void* __restrict__ Cout, int M, int N, int K)
{
    __shared__ ushort As[128 * 40];
    __shared__ ushort Bs[128 * 40];

    const int tid  = threadIdx.x;
    const int wave = tid >> 6;
    const int lane = tid & 63;
    const int quad = lane >> 4;
    const int l16  = lane & 15;
    const int wr   = (wave >> 1) * 64;     // wave row offset in tile
    const int wc   = (wave & 1) * 64;      // wave col offset in tile
    const int bm   = blockIdx.y * 128;
    const int bn   = blockIdx.x * 128;

    // staging map: chunk c -> row=c>>2 (0..127), kc=c&3 (8 bf16 per chunk)
    const int r0 = tid >> 2,        kc0 = tid & 3;          // chunk tid
    const int r1 = (tid + 256) >> 2, kc1 = tid & 3;         // chunk tid+256

    f32x4 acc[4][4] = {};

    for (int k0 = 0; k0 < K; k0 += 32) {
        float4 a0 = *(const float4*)(A  + (size_t)(bm + r0) * K + k0 + kc0 * 8);
        float4 a1 = *(const float4*)(A  + (size_t)(bm + r1) * K + k0 + kc1 * 8);
        float4 b0 = *(const float4*)(Bt + (size_t)(bn + r0) * K + k0 + kc0 * 8);
        float4 b1 = *(const float4*)(Bt + (size_t)(bn + r1) * K + k0 + kc1 * 8);
        __syncthreads();   // protect LDS from previous iteration's readers
        *(float4*)&As[r0 * 40 + kc0 * 8] = a0;
        *(float4*)&As[r1 * 40 + kc1 * 8] = a1;
        *(float4*)&Bs[r0 * 40 + kc0 * 8] = b0;
        *(float4*)&Bs[r1 * 40 + kc1 * 8] = b1;
        __syncthreads();

        bf16x8 af[4], bfr[4];
#pragma unroll
        for (int mi = 0; mi < 4; ++mi)
            af[mi] = *(const bf16x8*)&As[(wr + mi * 16 + l16) * 40 + quad * 8];
#pragma unroll
        for (int ni = 0; ni < 4; ++ni)
            bfr[ni] = *(const bf16x8*)&Bs[(wc + ni * 16 + l16) * 40 + quad * 8];
#pragma unroll
        for (int mi = 0; mi < 4; ++mi)
#pragma unroll
            for (int ni = 0; ni < 4; ++ni)
                acc[mi][ni] = __builtin_amdgcn_mfma_f32_16x16x32_bf16(
                    af[mi], bfr[ni], acc[mi][ni], 0, 0, 0);
    }

#pragma unroll
    for (int mi = 0; mi < 4; ++mi) {
#pragma unroll
        for (int ni = 0; ni < 4; ++ni) {
            const int col = bn + wc + ni * 16 + l16;
            const float bb = bias[col];
#pragma unroll
            for (int r = 0; r < 4; ++r) {
                const int row = bm + wr + mi * 16 + quad * 4 + r;
                const size_t idx = (size_t)row * N + col;
                float c = acc[mi][ni][r] + bb;
                if (RELU)  c = fmaxf(c, 0.f);
                if (RESID) c += resid[idx];
                if (OUT_BF16) ((ushort*)Cout)[idx] = f2b(c);
                else          ((float*)Cout)[idx]  = c;
            }
        }
    }
}

// ---------------------------------------------------------------------------
// fp32 tiled GEMM (kept for the small off/attn projections, N=192/96)
// ---------------------------------------------------------------------------
__global__ __launch_bounds__(256)
void gemm_k(const float* __restrict__ A, const float* __restrict__ B,
            const float* __restrict__ bias, float* C, int M, int N, int K)
{
    __shared__ float As[16][68];
    __shared__ float Bs[16][64];

    const int tid = threadIdx.x;
    const int bm  = blockIdx.y * 64;
    const int bn  = blockIdx.x * 64;
    const int tx  = tid & 15;
    const int ty  = tid >> 4;
    const int aRow = tid >> 2;
    const int aCol = (tid & 3) << 2;
    const int bRow = tid >> 4;
    const int bCol = (tid & 15) << 2;

    float acc[4][4] = {};

    for (int k0 = 0; k0 < K; k0 += 16) {
        float4 av = *(const float4*)(A + (size_t)(bm + aRow) * K + k0 + aCol);
        float4 bv = make_float4(0.f, 0.f, 0.f, 0.f);
        if (bn + bCol < N)
            bv = *(const float4*)(B + (size_t)(k0 + bRow) * N + bn + bCol);

        As[aCol + 0][aRow] = av.x;
        As[aCol + 1][aRow] = av.y;
        As[aCol + 2][aRow] = av.z;
        As[aCol + 3][aRow] = av.w;
        *(float4*)&Bs[bRow][bCol] = bv;
        __syncthreads();

#pragma unroll
        for (int kk = 0; kk < 16; ++kk) {
            float4 a = *(const float4*)&As[kk][ty * 4];
            float4 b = *(const float4*)&Bs[kk][tx * 4];
#pragma unroll
            for (int i = 0; i < 4; ++i) {
                const float ai = (&a.x)[i];
                acc[i][0] = fmaf(ai, b.x, acc[i][0]);
                acc[i][1] = fmaf(ai, b.y, acc[i][1]);
                acc[i][2] = fmaf(ai, b.z, acc[i][2]);
                acc[i][3] = fmaf(ai, b.w, acc[i][3]);
            }
        }
        __syncthreads();
    }

#pragma unroll
    for (int i = 0; i < 4; ++i) {
        const int row = bm + ty * 4 + i;
#pragma unroll
        for (int j = 0; j < 4; ++j) {
            const int col = bn + tx * 4 + j;
            if (col < N)
                C[(size_t)row * N + col] = acc[i][j] + bias[col];
        }
    }
}

// ---------------------------------------------------------------------------
// Fused softmax + deformable bilinear sampling. Output bf16 (feeds MFMA gemm).
// ---------------------------------------------------------------------------
__global__ __launch_bounds__(256)
void sample_k(const float* __restrict__ value, const float* __restrict__ offraw,
              const float* __restrict__ attnraw, ushort* __restrict__ acc)
{
    __shared__ float sOff[N_HEADS * N_LEVELS * N_POINTS * 2]; // 192
    __shared__ float sAttn[N_HEADS][N_LEVELS * N_POINTS];     // 96

    const int bq = blockIdx.x;
    const int n  = bq >> 14;
    const int q  = bq & 16383;
    const int d  = threadIdx.x;
    const int h  = threadIdx.y;
    const int tid = h * 32 + d;

    if (tid < 192) sOff[tid] = offraw[(size_t)bq * 192 + tid];
    if (tid >= 160) {
        const int j = tid - 160;        // 0..95
        sAttn[j / 12][j % 12] = attnraw[(size_t)bq * 96 + j];
    }
    __syncthreads();

    if (d == 0) {
        float m = sAttn[h][0];
#pragma unroll
        for (int j = 1; j < 12; ++j) m = fmaxf(m, sAttn[h][j]);
        float s = 0.f;
#pragma unroll
        for (int j = 0; j < 12; ++j) {
            const float e = __expf(sAttn[h][j] - m);
            sAttn[h][j] = e;
            s += e;
        }
        const float inv = 1.f / s;
#pragma unroll
        for (int j = 0; j < 12; ++j) sAttn[h][j] *= inv;
    }
    __syncthreads();

    const float refx = ((q & 127) + 0.5f) * (1.f / 128.f);
    const float refy = ((q >> 7) + 0.5f) * (1.f / 128.f);

    const int HW[3]  = {128, 64, 32};
    const int LSI[3] = {0, 16384, 20480};

    float a = 0.f;
    const float* vbase = value + (size_t)n * LENIN * D_MODEL + h * D_HEAD + d;

#pragma unroll
    for (int l = 0; l < N_LEVELS; ++l) {
        const int   W  = HW[l];
        const float fW = (float)W;
        const float* vlev = vbase + (size_t)LSI[l] * D_MODEL;
#pragma unroll
        for (int p = 0; p < N_POINTS; ++p) {
            const int ob = (h * N_LEVELS + l) * (N_POINTS * 2) + p * 2;
            const float aw = sAttn[h][l * 4 + p];
            const float x = (refx + sOff[ob + 0] / fW) * fW - 0.5f;
            const float y = (refy + sOff[ob + 1] / fW) * fW - 0.5f;
            const float x0 = floorf(x), y0 = floorf(y);
            const float dx = x - x0,   dy = y - y0;
#pragma unroll
            for (int cy = 0; cy < 2; ++cy) {
#pragma unroll
                for (int cx = 0; cx < 2; ++cx) {
                    const float ix = x0 + (float)cx;
                    const float iy = y0 + (float)cy;
                    const float w  = (cx ? dx : 1.f - dx) * (cy ? dy : 1.f - dy);
                    const bool valid = (ix >= 0.f) && (ix <= fW - 1.f) &&
                                       (iy >= 0.f) && (iy <= fW - 1.f);
                    const int xi = min(max((int)ix, 0), W - 1);
                    const int yi = min(max((int)iy, 0), W - 1);
                    const float g = vlev[(size_t)(yi * W + xi) * D_MODEL];
                    a = fmaf(valid ? w * aw : 0.f, g, a);
                }
            }
        }
    }
    acc[(size_t)bq * D_MODEL + h * D_HEAD + d] = f2b(a);
}

// ---------------------------------------------------------------------------
// LayerNorm over 256, output bf16 (feeds FFN1 MFMA gemm).
// ---------------------------------------------------------------------------
__global__ __launch_bounds__(256)
void ln_k(const float* __restrict__ x, const float* __restrict__ gamma,
          const float* __restrict__ beta, ushort* __restrict__ out)
{
    const int wave = threadIdx.x >> 6;
    const int lane = threadIdx.x & 63;
    const size_t row = (size_t)blockIdx.x * 4 + wave;

    const float4 v = *(const float4*)(x + row * 256 + lane * 4);
    float s  = v.x + v.y + v.z + v.w;
    float s2 = v.x * v.x + v.y * v.y + v.z * v.z + v.w * v.w;
#pragma unroll
    for (int off = 32; off > 0; off >>= 1) {
        s  += __shfl_xor(s, off);
        s2 += __shfl_xor(s2, off);
    }
    const float mu  = s * (1.f / 256.f);
    const float var = s2 * (1.f / 256.f) - mu * mu;
    const float r   = rsqrtf(var + 1e-5f);

    const float4 g = *(const float4*)(gamma + lane * 4);
    const float4 b = *(const float4*)(beta + lane * 4);
    ushort4 o;
    o.x = f2b((v.x - mu) * r * g.x + b.x);
    o.y = f2b((v.y - mu) * r * g.y + b.y);
    o.z = f2b((v.z - mu) * r * g.z + b.z);
    o.w = f2b((v.w - mu) * r * g.w + b.w);
    *(ushort4*)(out + row * 256 + lane * 4) = o;
}

// ---------------------------------------------------------------------------
// fp32 -> bf16 (flat, n % 4 == 0)
// ---------------------------------------------------------------------------
__global__ __launch_bounds__(256)
void f2b_k(const float* __restrict__ x, ushort* __restrict__ y, int n4)
{
    const int i = blockIdx.x * 256 + threadIdx.x;
    if (i < n4) {
        const float4 v = ((const float4*)x)[i];
        ushort4 o = { f2b(v.x), f2b(v.y), f2b(v.z), f2b(v.w) };
        ((ushort4*)y)[i] = o;
    }
}

// fp32 [K][N] -> bf16 [N][K] transpose-convert (small weight matrices)
__global__ __launch_bounds__(256)
void tconv_k(const float* __restrict__ w, ushort* __restrict__ wT, int K, int N)
{
    const int i = blockIdx.x * 256 + threadIdx.x;
    if (i < K * N) {
        const int k = i / N, n = i - k * N;
        wT[(size_t)n * K + k] = f2b(w[i]);
    }
}

// ---------------------------------------------------------------------------
extern "C" void kernel_launch(void* const* d_in, const int* in_sizes, int n_in,
                              void* d_out, int out_size, void* d_ws, size_t ws_size,
                              hipStream_t stream)
{
    const float* src     = (const float*)d_in[0];
    const float* flow    = (const float*)d_in[1];
    const float* w_value = (const float*)d_in[4];
    const float* b_value = (const float*)d_in[5];
    const float* w_off   = (const float*)d_in[6];
    const float* b_off   = (const float*)d_in[7];
    const float* w_attn  = (const float*)d_in[8];
    const float* b_attn  = (const float*)d_in[9];
    const float* w_out   = (const float*)d_in[10];
    const float* b_out   = (const float*)d_in[11];
    const float* gamma   = (const float*)d_in[12];
    const float* beta    = (const float*)d_in[13];
    const float* w1      = (const float*)d_in[14];
    const float* b1      = (const float*)d_in[15];
    const float* w2      = (const float*)d_in[16];
    const float* b2      = (const float*)d_in[17];
    float* out = (float*)d_out;
    char*  wsb = (char*)d_ws;

    // Byte-offset workspace layout (lifetime-aliased), total 123.0 MB:
    //   [0, 67108864)           ffn1_bf (step7+) ; earlier: src_bf [0,22020096)
    //                           + value fp32 [22020096, 66060288)
    //   [67108864, 92274688)    offraw fp32 (dead after sampler) -> ln_bf
    //   [92274688, 104857600)   attnraw fp32
    //   [104857600, 121634816)  acc_bf
    //   [121634816, ...)        bf16 transposed weights
    ushort* ffn1_bf = (ushort*)(wsb);
    ushort* src_bf  = (ushort*)(wsb);
    float*  value   = (float*) (wsb + 22020096);
    float*  offraw  = (float*) (wsb + 67108864);
    ushort* ln_bf   = (ushort*)(wsb + 67108864);
    float*  attnraw = (float*) (wsb + 92274688);
    ushort* acc_bf  = (ushort*)(wsb + 104857600);
    ushort* wvT     = (ushort*)(wsb + 121634816);   // [256][256]
    ushort* woT     = (ushort*)(wsb + 121765888);   // [256][256]
    ushort* w1T     = (ushort*)(wsb + 121896960);   // [1024][256]
    ushort* w2T     = (ushort*)(wsb + 122421248);   // [256][1024]

    const int Mq = NB * LQ;     // 32768
    const int Mv = NB * LENIN;  // 43008

    // 0. dtype conversions
    f2b_k<<<(Mv * D_MODEL / 4 + 255) / 256, 256, 0, stream>>>(src, src_bf, Mv * D_MODEL / 4);
    tconv_k<<<(256 * 256 + 255) / 256, 256, 0, stream>>>(w_value, wvT, 256, 256);
    tconv_k<<<(256 * 256 + 255) / 256, 256, 0, stream>>>(w_out,  woT, 256, 256);
    tconv_k<<<(256 * 1024 + 255) / 256, 256, 0, stream>>>(w1, w1T, 256, 1024);
    tconv_k<<<(1024 * 256 + 255) / 256, 256, 0, stream>>>(w2, w2T, 1024, 256);

    // 1. value = src @ w_value + b_value          [43008 x 256] fp32 out
    mfma_gemm<false, false, false><<<dim3(2, Mv / 128), 256, 0, stream>>>(
        src_bf, wvT, b_value, nullptr, value, Mv, 256, 256);

    // 2/3. offset & attention projections (fp32, small)
    gemm_k<<<dim3(3, Mq / 64), 256, 0, stream>>>(flow, w_off, b_off, offraw, Mq, 192, D_FLOW);
    gemm_k<<<dim3(2, Mq / 64), 256, 0, stream>>>(flow, w_attn, b_attn, attnraw, Mq, 96, D_FLOW);

    // 4. deformable sampling (fused softmax)      [32768 x 256] bf16 out
    sample_k<<<Mq, dim3(32, 8), 0, stream>>>(value, offraw, attnraw, acc_bf);

    // 5. x = acc @ w_out + b_out -> d_out fp32
    mfma_gemm<false, false, false><<<dim3(2, Mq / 128), 256, 0, stream>>>(
        acc_bf, woT, b_out, nullptr, out, Mq, 256, 256);

    // 6. ln = LayerNorm(x) -> bf16
    ln_k<<<Mq / 4, 256, 0, stream>>>(out, gamma, beta, ln_bf);

    // 7. ffn1 = relu(ln @ w1 + b1) -> bf16        [32768 x 1024]
    mfma_gemm<true, false, true><<<dim3(8, Mq / 128), 256, 0, stream>>>(
        ln_bf, w1T, b1, nullptr, ffn1_bf, Mq, D_FFN, 256);

    // 8. out = x + ffn1 @ w2 + b2                 [32768 x 256]
    mfma_gemm<false, true, false><<<dim3(2, Mq / 128), 256, 0, stream>>>(
        ffn1_bf, w2T, b2, out, out, Mq, 256, D_FFN);
}

// Round 4
// 370.318 us; speedup vs baseline: 2.6817x; 1.3551x over previous
//
#include <hip/hip_runtime.h>
#include <cstdint>
#include <cstddef>

#define D_MODEL  256
#define D_FLOW   128
#define D_FFN    1024
#define N_HEADS  8
#define N_LEVELS 3
#define N_POINTS 4
#define D_HEAD   32
#define LQ       16384
#define LENIN    21504
#define NB       2

typedef unsigned short ushort;
typedef __attribute__((ext_vector_type(8))) short bf16x8;   // 8 bf16 in 4 VGPRs
typedef __attribute__((ext_vector_type(4))) float f32x4;

__device__ __forceinline__ ushort f2b(float f) {            // fp32 -> bf16 RNE
    uint32_t u = __float_as_uint(f);
    uint32_t r = (u + 0x7fffu + ((u >> 16) & 1u)) >> 16;
    return (ushort)r;
}

// ---------------------------------------------------------------------------
// bf16 MFMA GEMM: C[M,N] = A[M,K] @ B^T[N,K] + bias[N]  (B passed pre-transposed)
// BM=BN=128, BK=32. 256 threads = 4 waves in 2x2; each wave: 4x4 tiles of
// 16x16x32 MFMA. LDS rows padded 32->40 bf16 (80B stride -> 2-way max, free).
// Requires M%128==0, N%128==0, K%32==0.
// ---------------------------------------------------------------------------
template<bool RELU, bool RESID, bool OUT_BF16>
__global__ __launch_bounds__(256)
void mfma_gemm(const ushort* __restrict__ A, const ushort* __restrict__ Bt,
               const float* __restrict__ bias, const float* __restrict__ resid,
               void* __restrict__ Cout, int M, int N, int K)
{
    __shared__ ushort As[128 * 40];
    __shared__ ushort Bs[128 * 40];

    const int tid  = threadIdx.x;
    const int wave = tid >> 6;
    const int lane = tid & 63;
    const int quad = lane >> 4;
    const int l16  = lane & 15;
    const int wr   = (wave >> 1) * 64;
    const int wc   = (wave & 1) * 64;
    const int bm   = blockIdx.y * 128;
    const int bn   = blockIdx.x * 128;

    const int r0 = tid >> 2,         kc0 = tid & 3;
    const int r1 = (tid + 256) >> 2, kc1 = tid & 3;

    f32x4 acc[4][4] = {};

    for (int k0 = 0; k0 < K; k0 += 32) {
        float4 a0 = *(const float4*)(A  + (size_t)(bm + r0) * K + k0 + kc0 * 8);
        float4 a1 = *(const float4*)(A  + (size_t)(bm + r1) * K + k0 + kc1 * 8);
        float4 b0 = *(const float4*)(Bt + (size_t)(bn + r0) * K + k0 + kc0 * 8);
        float4 b1 = *(const float4*)(Bt + (size_t)(bn + r1) * K + k0 + kc1 * 8);
        __syncthreads();
        *(float4*)&As[r0 * 40 + kc0 * 8] = a0;
        *(float4*)&As[r1 * 40 + kc1 * 8] = a1;
        *(float4*)&Bs[r0 * 40 + kc0 * 8] = b0;
        *(float4*)&Bs[r1 * 40 + kc1 * 8] = b1;
        __syncthreads();

        bf16x8 af[4], bfr[4];
#pragma unroll
        for (int mi = 0; mi < 4; ++mi)
            af[mi] = *(const bf16x8*)&As[(wr + mi * 16 + l16) * 40 + quad * 8];
#pragma unroll
        for (int ni = 0; ni < 4; ++ni)
            bfr[ni] = *(const bf16x8*)&Bs[(wc + ni * 16 + l16) * 40 + quad * 8];
#pragma unroll
        for (int mi = 0; mi < 4; ++mi)
#pragma unroll
            for (int ni = 0; ni < 4; ++ni)
                acc[mi][ni] = __builtin_amdgcn_mfma_f32_16x16x32_bf16(
                    af[mi], bfr[ni], acc[mi][ni], 0, 0, 0);
    }

#pragma unroll
    for (int mi = 0; mi < 4; ++mi) {
#pragma unroll
        for (int ni = 0; ni < 4; ++ni) {
            const int col = bn + wc + ni * 16 + l16;
            const float bb = bias[col];
#pragma unroll
            for (int r = 0; r < 4; ++r) {
                const int row = bm + wr + mi * 16 + quad * 4 + r;
                const size_t idx = (size_t)row * N + col;
                float c = acc[mi][ni][r] + bb;
                if (RELU)  c = fmaxf(c, 0.f);
                if (RESID) c += resid[idx];
                if (OUT_BF16) ((ushort*)Cout)[idx] = f2b(c);
                else          ((float*)Cout)[idx]  = c;
            }
        }
    }
}

// ---------------------------------------------------------------------------
// fp32 tiled GEMM (small off/attn projections, N=192/96)
// ---------------------------------------------------------------------------
__global__ __launch_bounds__(256)
void gemm_k(const float* __restrict__ A, const float* __restrict__ B,
            const float* __restrict__ bias, float* C, int M, int N, int K)
{
    __shared__ float As[16][68];
    __shared__ float Bs[16][64];

    const int tid = threadIdx.x;
    const int bm  = blockIdx.y * 64;
    const int bn  = blockIdx.x * 64;
    const int tx  = tid & 15;
    const int ty  = tid >> 4;
    const int aRow = tid >> 2;
    const int aCol = (tid & 3) << 2;
    const int bRow = tid >> 4;
    const int bCol = (tid & 15) << 2;

    float acc[4][4] = {};

    for (int k0 = 0; k0 < K; k0 += 16) {
        float4 av = *(const float4*)(A + (size_t)(bm + aRow) * K + k0 + aCol);
        float4 bv = make_float4(0.f, 0.f, 0.f, 0.f);
        if (bn + bCol < N)
            bv = *(const float4*)(B + (size_t)(k0 + bRow) * N + bn + bCol);

        As[aCol + 0][aRow] = av.x;
        As[aCol + 1][aRow] = av.y;
        As[aCol + 2][aRow] = av.z;
        As[aCol + 3][aRow] = av.w;
        *(float4*)&Bs[bRow][bCol] = bv;
        __syncthreads();

#pragma unroll
        for (int kk = 0; kk < 16; ++kk) {
            float4 a = *(const float4*)&As[kk][ty * 4];
            float4 b = *(const float4*)&Bs[kk][tx * 4];
#pragma unroll
            for (int i = 0; i < 4; ++i) {
                const float ai = (&a.x)[i];
                acc[i][0] = fmaf(ai, b.x, acc[i][0]);
                acc[i][1] = fmaf(ai, b.y, acc[i][1]);
                acc[i][2] = fmaf(ai, b.z, acc[i][2]);
                acc[i][3] = fmaf(ai, b.w, acc[i][3]);
            }
        }
        __syncthreads();
    }

#pragma unroll
    for (int i = 0; i < 4; ++i) {
        const int row = bm + ty * 4 + i;
#pragma unroll
        for (int j = 0; j < 4; ++j) {
            const int col = bn + tx * 4 + j;
            if (col < N)
                C[(size_t)row * N + col] = acc[i][j] + bias[col];
        }
    }
}

// ---------------------------------------------------------------------------
// Fused softmax + deformable bilinear sampling, wave-per-query.
// Block = 256 threads = 4 waves = 4 queries. Lane: h = lane>>3 (head),
// cg = lane&7 (4-channel group). Each lane holds float4 of channels.
// Per point: 8 lanes/head share address math (vs 32 in round-3), 4 float4
// gathers + 16 FMA. 48 VMEM instr/query (was 192).
// ---------------------------------------------------------------------------
__global__ __launch_bounds__(256)
void sample_k(const float* __restrict__ value, const float* __restrict__ offraw,
              const float* __restrict__ attnraw, ushort* __restrict__ acc)
{
    __shared__ float sOff[4][192];
    __shared__ float sAttn[4][96];

    const int tid = threadIdx.x;
    const int bq0 = blockIdx.x * 4;

    for (int i = tid; i < 4 * 288; i += 256) {
        const int qw = i / 288, j = i - qw * 288;
        if (j < 192) sOff[qw][j] = offraw[(size_t)(bq0 + qw) * 192 + j];
        else         sAttn[qw][j - 192] = attnraw[(size_t)(bq0 + qw) * 96 + (j - 192)];
    }
    __syncthreads();

    if (tid < 32) {            // 4 queries x 8 heads: softmax over 12
        const int qw = tid >> 3, h = tid & 7;
        float* row = &sAttn[qw][h * 12];
        float m = row[0];
#pragma unroll
        for (int j = 1; j < 12; ++j) m = fmaxf(m, row[j]);
        float s = 0.f;
#pragma unroll
        for (int j = 0; j < 12; ++j) { const float e = __expf(row[j] - m); row[j] = e; s += e; }
        const float inv = 1.f / s;
#pragma unroll
        for (int j = 0; j < 12; ++j) row[j] *= inv;
    }
    __syncthreads();

    const int qw   = tid >> 6;     // wave index = query slot
    const int lane = tid & 63;
    const int h    = lane >> 3;
    const int cg   = lane & 7;
    const int bq   = bq0 + qw;
    const int n    = bq >> 14;
    const int q    = bq & 16383;

    const float qx = (float)(q & 127) + 0.5f;   // level-0 pixel units
    const float qy = (float)(q >> 7) + 0.5f;

    const int HW[3]  = {128, 64, 32};
    const int LSI[3] = {0, 16384, 20480};

    float4 a = make_float4(0.f, 0.f, 0.f, 0.f);
    const float* vbase = value + (size_t)n * LENIN * D_MODEL + h * D_HEAD + cg * 4;

#pragma unroll
    for (int l = 0; l < N_LEVELS; ++l) {
        const int   W     = HW[l];
        const float scale = (float)W * (1.f / 128.f);
        const float cx    = qx * scale - 0.5f;   // x = cx + off_x  (algebraic fold)
        const float cy    = qy * scale - 0.5f;
        const float* vlev = vbase + (size_t)LSI[l] * D_MODEL;
#pragma unroll
        for (int p = 0; p < N_POINTS; ++p) {
            const int ob = (h * N_LEVELS + l) * (N_POINTS * 2) + p * 2;
            const float aw = sAttn[qw][h * 12 + l * 4 + p];
            const float x = cx + sOff[qw][ob + 0];
            const float y = cy + sOff[qw][ob + 1];
            const float x0f = floorf(x), y0f = floorf(y);
            const float dx = x - x0f, dy = y - y0f;
            const int x0 = (int)x0f, y0 = (int)y0f;
#pragma unroll
            for (int cyy = 0; cyy < 2; ++cyy) {
#pragma unroll
                for (int cxx = 0; cxx < 2; ++cxx) {
                    const int ix = x0 + cxx, iy = y0 + cyy;
                    const float w = (cxx ? dx : 1.f - dx) * (cyy ? dy : 1.f - dy);
                    const bool valid = (ix >= 0) && (ix < W) && (iy >= 0) && (iy < W);
                    const int xi = min(max(ix, 0), W - 1);
                    const int yi = min(max(iy, 0), W - 1);
                    const float4 g = *(const float4*)(vlev + (size_t)(yi * W + xi) * D_MODEL);
                    const float wv = valid ? w * aw : 0.f;
                    a.x = fmaf(wv, g.x, a.x);
                    a.y = fmaf(wv, g.y, a.y);
                    a.z = fmaf(wv, g.z, a.z);
                    a.w = fmaf(wv, g.w, a.w);
                }
            }
        }
    }
    ushort4 o = { f2b(a.x), f2b(a.y), f2b(a.z), f2b(a.w) };
    *(ushort4*)(acc + (size_t)bq * D_MODEL + h * D_HEAD + cg * 4) = o;
}

// ---------------------------------------------------------------------------
// LayerNorm over 256, output bf16 (feeds FFN1 MFMA gemm).
// ---------------------------------------------------------------------------
__global__ __launch_bounds__(256)
void ln_k(const float* __restrict__ x, const float* __restrict__ gamma,
          const float* __restrict__ beta, ushort* __restrict__ out)
{
    const int wave = threadIdx.x >> 6;
    const int lane = threadIdx.x & 63;
    const size_t row = (size_t)blockIdx.x * 4 + wave;

    const float4 v = *(const float4*)(x + row * 256 + lane * 4);
    float s  = v.x + v.y + v.z + v.w;
    float s2 = v.x * v.x + v.y * v.y + v.z * v.z + v.w * v.w;
#pragma unroll
    for (int off = 32; off > 0; off >>= 1) {
        s  += __shfl_xor(s, off);
        s2 += __shfl_xor(s2, off);
    }
    const float mu  = s * (1.f / 256.f);
    const float var = s2 * (1.f / 256.f) - mu * mu;
    const float r   = rsqrtf(var + 1e-5f);

    const float4 g = *(const float4*)(gamma + lane * 4);
    const float4 b = *(const float4*)(beta + lane * 4);
    ushort4 o;
    o.x = f2b((v.x - mu) * r * g.x + b.x);
    o.y = f2b((v.y - mu) * r * g.y + b.y);
    o.z = f2b((v.z - mu) * r * g.z + b.z);
    o.w = f2b((v.w - mu) * r * g.w + b.w);
    *(ushort4*)(out + row * 256 + lane * 4) = o;
}

// ---------------------------------------------------------------------------
__global__ __launch_bounds__(256)
void f2b_k(const float* __restrict__ x, ushort* __restrict__ y, int n4)
{
    const int i = blockIdx.x * 256 + threadIdx.x;
    if (i < n4) {
        const float4 v = ((const float4*)x)[i];
        ushort4 o = { f2b(v.x), f2b(v.y), f2b(v.z), f2b(v.w) };
        ((ushort4*)y)[i] = o;
    }
}

__global__ __launch_bounds__(256)
void tconv_k(const float* __restrict__ w, ushort* __restrict__ wT, int K, int N)
{
    const int i = blockIdx.x * 256 + threadIdx.x;
    if (i < K * N) {
        const int k = i / N, n = i - k * N;
        wT[(size_t)n * K + k] = f2b(w[i]);
    }
}

// ---------------------------------------------------------------------------
extern "C" void kernel_launch(void* const* d_in, const int* in_sizes, int n_in,
                              void* d_out, int out_size, void* d_ws, size_t ws_size,
                              hipStream_t stream)
{
    const float* src     = (const float*)d_in[0];
    const float* flow    = (const float*)d_in[1];
    const float* w_value = (const float*)d_in[4];
    const float* b_value = (const float*)d_in[5];
    const float* w_off   = (const float*)d_in[6];
    const float* b_off   = (const float*)d_in[7];
    const float* w_attn  = (const float*)d_in[8];
    const float* b_attn  = (const float*)d_in[9];
    const float* w_out   = (const float*)d_in[10];
    const float* b_out   = (const float*)d_in[11];
    const float* gamma   = (const float*)d_in[12];
    const float* beta    = (const float*)d_in[13];
    const float* w1      = (const float*)d_in[14];
    const float* b1      = (const float*)d_in[15];
    const float* w2      = (const float*)d_in[16];
    const float* b2      = (const float*)d_in[17];
    float* out = (float*)d_out;
    char*  wsb = (char*)d_ws;

    ushort* ffn1_bf = (ushort*)(wsb);
    ushort* src_bf  = (ushort*)(wsb);
    float*  value   = (float*) (wsb + 22020096);
    float*  offraw  = (float*) (wsb + 67108864);
    ushort* ln_bf   = (ushort*)(wsb + 67108864);
    float*  attnraw = (float*) (wsb + 92274688);
    ushort* acc_bf  = (ushort*)(wsb + 104857600);
    ushort* wvT     = (ushort*)(wsb + 121634816);   // [256][256]
    ushort* woT     = (ushort*)(wsb + 121765888);   // [256][256]
    ushort* w1T     = (ushort*)(wsb + 121896960);   // [1024][256]
    ushort* w2T     = (ushort*)(wsb + 122421248);   // [256][1024]

    const int Mq = NB * LQ;     // 32768
    const int Mv = NB * LENIN;  // 43008

    // 0. dtype conversions
    f2b_k<<<(Mv * D_MODEL / 4 + 255) / 256, 256, 0, stream>>>(src, src_bf, Mv * D_MODEL / 4);
    tconv_k<<<(256 * 256 + 255) / 256, 256, 0, stream>>>(w_value, wvT, 256, 256);
    tconv_k<<<(256 * 256 + 255) / 256, 256, 0, stream>>>(w_out,  woT, 256, 256);
    tconv_k<<<(256 * 1024 + 255) / 256, 256, 0, stream>>>(w1, w1T, 256, 1024);
    tconv_k<<<(1024 * 256 + 255) / 256, 256, 0, stream>>>(w2, w2T, 1024, 256);

    // 1. value = src @ w_value + b_value          [43008 x 256] fp32 out
    mfma_gemm<false, false, false><<<dim3(2, Mv / 128), 256, 0, stream>>>(
        src_bf, wvT, b_value, nullptr, value, Mv, 256, 256);

    // 2/3. offset & attention projections (fp32, small)
    gemm_k<<<dim3(3, Mq / 64), 256, 0, stream>>>(flow, w_off, b_off, offraw, Mq, 192, D_FLOW);
    gemm_k<<<dim3(2, Mq / 64), 256, 0, stream>>>(flow, w_attn, b_attn, attnraw, Mq, 96, D_FLOW);

    // 4. deformable sampling (fused softmax)      [32768 x 256] bf16 out
    sample_k<<<Mq / 4, 256, 0, stream>>>(value, offraw, attnraw, acc_bf);

    // 5. x = acc @ w_out + b_out -> d_out fp32
    mfma_gemm<false, false, false><<<dim3(2, Mq / 128), 256, 0, stream>>>(
        acc_bf, woT, b_out, nullptr, out, Mq, 256, 256);

    // 6. ln = LayerNorm(x) -> bf16
    ln_k<<<Mq / 4, 256, 0, stream>>>(out, gamma, beta, ln_bf);

    // 7. ffn1 = relu(ln @ w1 + b1) -> bf16        [32768 x 1024]
    mfma_gemm<true, false, true><<<dim3(8, Mq / 128), 256, 0, stream>>>(
        ln_bf, w1T, b1, nullptr, ffn1_bf, Mq, D_FFN, 256);

    // 8. out = x + ffn1 @ w2 + b2                 [32768 x 256]
    mfma_gemm<false, true, false><<<dim3(2, Mq / 128), 256, 0, stream>>>(
        ffn1_bf, w2T, b2, out, out, Mq, 256, D_FFN);
}

// Round 5
// 312.119 us; speedup vs baseline: 3.1818x; 1.1865x over previous
//
#include <hip/hip_runtime.h>
#include <cstdint>
#include <cstddef>

#define D_MODEL  256
#define D_FLOW   128
#define D_FFN    1024
#define N_HEADS  8
#define N_LEVELS 3
#define N_POINTS 4
#define D_HEAD   32
#define LQ       16384
#define LENIN    21504
#define NB       2

typedef unsigned short ushort;
typedef __attribute__((ext_vector_type(8))) short bf16x8;   // 8 bf16 in 4 VGPRs
typedef __attribute__((ext_vector_type(4))) float f32x4;

__device__ __forceinline__ ushort f2b(float f) {            // fp32 -> bf16 RNE
    uint32_t u = __float_as_uint(f);
    uint32_t r = (u + 0x7fffu + ((u >> 16) & 1u)) >> 16;
    return (ushort)r;
}

// async 16B global->LDS copy; LDS dest = wave-uniform base + lane*16
__device__ __forceinline__ void gl_lds16(const void* g, void* l) {
    __builtin_amdgcn_global_load_lds(
        (const __attribute__((address_space(1))) unsigned int*)g,
        (__attribute__((address_space(3))) unsigned int*)l,
        16, 0, 0);
}

// ---------------------------------------------------------------------------
// bf16 MFMA GEMM: C[M,N] = A[M,K] @ B^T[N,K] + bias[N]  (B pre-transposed)
// BM=BN=128, BK=32, 256 thr = 4 waves (2x2), 4x4 16x16x32 MFMA tiles/wave.
// m97-style staging: global_load_lds dwordx4, unpadded LDS [128][32]bf16 with
// 16B-chunk XOR swizzle (chunk ^= row&3) to cut ds_read_b128 bank conflicts.
// Requires M%128==0, N%128==0, K%32==0.
// ---------------------------------------------------------------------------
template<bool RELU, bool RESID, bool OUT_BF16>
__global__ __launch_bounds__(256)
void mfma_gemm(const ushort* __restrict__ A, const ushort* __restrict__ Bt,
               const float* __restrict__ bias, const float* __restrict__ resid,
               void* __restrict__ Cout, int N, int K)
{
    __shared__ ushort As[128 * 32];
    __shared__ ushort Bs[128 * 32];

    const int tid  = threadIdx.x;
    const int wave = tid >> 6;
    const int lane = tid & 63;
    const int quad = lane >> 4;
    const int l16  = lane & 15;
    const int wr   = (wave >> 1) * 64;
    const int wc   = (wave & 1) * 64;
    const int bm   = blockIdx.y * 128;
    const int bn   = blockIdx.x * 128;

    // staging: wave covers rows [wave*32, wave*32+32): 2 issues x 16 rows,
    // 4 lanes/row x 16B. LDS layout = row-major [128][32] unpadded.
    const int sr   = lane >> 2;             // row within 16-row group
    const int sc   = lane & 3;              // chunk position in LDS (lane*16B)
    const int gch  = sc ^ (sr & 3);         // swizzled source chunk
    const int row0 = wave * 32 + sr;
    const int row1 = row0 + 16;

    const ushort* pA0 = A  + (size_t)(bm + row0) * K + gch * 8;
    const ushort* pA1 = A  + (size_t)(bm + row1) * K + gch * 8;
    const ushort* pB0 = Bt + (size_t)(bn + row0) * K + gch * 8;
    const ushort* pB1 = Bt + (size_t)(bn + row1) * K + gch * 8;
    ushort* lA0 = As + wave * 1024;         // 32 rows * 32 cols per wave
    ushort* lA1 = As + wave * 1024 + 512;
    ushort* lB0 = Bs + wave * 1024;
    ushort* lB1 = Bs + wave * 1024 + 512;

    f32x4 acc[4][4] = {};
    const int swz = l16 & 3;

    for (int k0 = 0; k0 < K; k0 += 32) {
        __syncthreads();                    // prior iteration's ds_reads done
        gl_lds16(pA0 + k0, lA0);
        gl_lds16(pA1 + k0, lA1);
        gl_lds16(pB0 + k0, lB0);
        gl_lds16(pB1 + k0, lB1);
        __syncthreads();                    // drains vmcnt(0): tile in LDS

        bf16x8 af[4], bfr[4];
#pragma unroll
        for (int mi = 0; mi < 4; ++mi)
            af[mi] = *(const bf16x8*)&As[(wr + mi * 16 + l16) * 32 + ((quad ^ swz) << 3)];
#pragma unroll
        for (int ni = 0; ni < 4; ++ni)
            bfr[ni] = *(const bf16x8*)&Bs[(wc + ni * 16 + l16) * 32 + ((quad ^ swz) << 3)];
#pragma unroll
        for (int mi = 0; mi < 4; ++mi)
#pragma unroll
            for (int ni = 0; ni < 4; ++ni)
                acc[mi][ni] = __builtin_amdgcn_mfma_f32_16x16x32_bf16(
                    af[mi], bfr[ni], acc[mi][ni], 0, 0, 0);
    }

#pragma unroll
    for (int mi = 0; mi < 4; ++mi) {
#pragma unroll
        for (int ni = 0; ni < 4; ++ni) {
            const int col = bn + wc + ni * 16 + l16;
            const float bb = bias[col];
#pragma unroll
            for (int r = 0; r < 4; ++r) {
                const int row = bm + wr + mi * 16 + quad * 4 + r;
                const size_t idx = (size_t)row * N + col;
                float c = acc[mi][ni][r] + bb;
                if (RELU)  c = fmaxf(c, 0.f);
                if (RESID) c += resid[idx];
                if (OUT_BF16) ((ushort*)Cout)[idx] = f2b(c);
                else          ((float*)Cout)[idx]  = c;
            }
        }
    }
}

// ---------------------------------------------------------------------------
// Fused softmax + deformable bilinear sampling. value in bf16.
// Block = 256 thr = 4 waves; 2 queries per wave (32 lanes each):
// lane -> qh = lane>>5, h = (lane>>2)&7, cg = lane&3 (8 bf16 channels).
// Validity folded into corner weights via unsigned compares; aw folded in wx.
// ---------------------------------------------------------------------------
__device__ __forceinline__ void acc8(float* a, uint4 g, float w) {
    a[0] = fmaf(w, __uint_as_float(g.x << 16), a[0]);
    a[1] = fmaf(w, __uint_as_float(g.x & 0xffff0000u), a[1]);
    a[2] = fmaf(w, __uint_as_float(g.y << 16), a[2]);
    a[3] = fmaf(w, __uint_as_float(g.y & 0xffff0000u), a[3]);
    a[4] = fmaf(w, __uint_as_float(g.z << 16), a[4]);
    a[5] = fmaf(w, __uint_as_float(g.z & 0xffff0000u), a[5]);
    a[6] = fmaf(w, __uint_as_float(g.w << 16), a[6]);
    a[7] = fmaf(w, __uint_as_float(g.w & 0xffff0000u), a[7]);
}

__global__ __launch_bounds__(256)
void sample_k(const ushort* __restrict__ value, const ushort* __restrict__ projc,
              ushort* __restrict__ acc)
{
    __shared__ float sOff[8][192];
    __shared__ float sAttn[8][96];

    const int tid = threadIdx.x;
    const int bq0 = blockIdx.x * 8;

    // stage + bf16->f32 convert proj rows (stride 384: 192 off + 96 attn + pad)
    for (int i = tid; i < 8 * 288; i += 256) {
        const int qw = i / 288, j = i - qw * 288;
        const float v = __uint_as_float((uint32_t)projc[(size_t)(bq0 + qw) * 384 + j] << 16);
        if (j < 192) sOff[qw][j] = v;
        else         sAttn[qw][j - 192] = v;
    }
    __syncthreads();

    if (tid < 64) {                        // 8 queries x 8 heads: softmax(12)
        const int qw = tid >> 3, h = tid & 7;
        float* row = &sAttn[qw][h * 12];
        float m = row[0];
#pragma unroll
        for (int j = 1; j < 12; ++j) m = fmaxf(m, row[j]);
        float s = 0.f;
#pragma unroll
        for (int j = 0; j < 12; ++j) { const float e = __expf(row[j] - m); row[j] = e; s += e; }
        const float inv = 1.f / s;
#pragma unroll
        for (int j = 0; j < 12; ++j) row[j] *= inv;
    }
    __syncthreads();

    const int wave = tid >> 6, lane = tid & 63;
    const int qh = lane >> 5;              // query within wave
    const int h  = (lane >> 2) & 7;
    const int cg = lane & 3;               // 8-channel group
    const int qw = wave * 2 + qh;
    const int bq = bq0 + qw;
    const int n  = bq >> 14;
    const int q  = bq & 16383;

    const float qx = (float)(q & 127) + 0.5f;   // level-0 pixel units
    const float qy = (float)(q >> 7) + 0.5f;

    const int LSIc[3] = {0, 16384, 20480};

    float a[8] = {0.f, 0.f, 0.f, 0.f, 0.f, 0.f, 0.f, 0.f};
    const ushort* vbase = value + (size_t)n * LENIN * D_MODEL + h * D_HEAD + cg * 8;

#pragma unroll
    for (int l = 0; l < N_LEVELS; ++l) {
        const int   W     = 128 >> l;
        const int   SH    = 7 - l;
        const float scale = 1.f / (float)(1 << l);
        const float cx    = qx * scale - 0.5f;
        const float cy    = qy * scale - 0.5f;
        const ushort* vlev = vbase + ((size_t)LSIc[l] << 8);
#pragma unroll
        for (int p = 0; p < N_POINTS; ++p) {
            const int ob = (h * N_LEVELS + l) * (N_POINTS * 2) + p * 2;
            const float aw = sAttn[qw][h * 12 + l * 4 + p];
            const float x = cx + sOff[qw][ob];
            const float y = cy + sOff[qw][ob + 1];
            const float x0f = floorf(x), y0f = floorf(y);
            const int x0 = (int)x0f, y0 = (int)y0f;
            const float dx = x - x0f, dy = y - y0f;
            float wx1 = dx * aw, wx0 = aw - wx1;        // (1-dx)*aw
            float wy1 = dy,      wy0 = 1.f - dy;
            if ((unsigned)x0       > (unsigned)(W - 1)) wx0 = 0.f;
            if ((unsigned)(x0 + 1) > (unsigned)(W - 1)) wx1 = 0.f;
            if ((unsigned)y0       > (unsigned)(W - 1)) wy0 = 0.f;
            if ((unsigned)(y0 + 1) > (unsigned)(W - 1)) wy1 = 0.f;
            const int xi0 = min(max(x0, 0), W - 1);
            const int xi1 = min(max(x0 + 1, 0), W - 1);
            const int yi0 = min(max(y0, 0), W - 1);
            const int yi1 = min(max(y0 + 1, 0), W - 1);
            const uint4 g00 = *(const uint4*)(vlev + ((size_t)((yi0 << SH) + xi0) << 8));
            const uint4 g01 = *(const uint4*)(vlev + ((size_t)((yi0 << SH) + xi1) << 8));
            const uint4 g10 = *(const uint4*)(vlev + ((size_t)((yi1 << SH) + xi0) << 8));
            const uint4 g11 = *(const uint4*)(vlev + ((size_t)((yi1 << SH) + xi1) << 8));
            acc8(a, g00, wx0 * wy0);
            acc8(a, g01, wx1 * wy0);
            acc8(a, g10, wx0 * wy1);
            acc8(a, g11, wx1 * wy1);
        }
    }

    const uint32_t o0 = (uint32_t)f2b(a[0]) | ((uint32_t)f2b(a[1]) << 16);
    const uint32_t o1 = (uint32_t)f2b(a[2]) | ((uint32_t)f2b(a[3]) << 16);
    const uint32_t o2 = (uint32_t)f2b(a[4]) | ((uint32_t)f2b(a[5]) << 16);
    const uint32_t o3 = (uint32_t)f2b(a[6]) | ((uint32_t)f2b(a[7]) << 16);
    const uint4 ov = {o0, o1, o2, o3};
    *(uint4*)(acc + (size_t)bq * D_MODEL + h * D_HEAD + cg * 8) = ov;
}

// ---------------------------------------------------------------------------
// LayerNorm over 256, fp32 in -> bf16 out.
// ---------------------------------------------------------------------------
__global__ __launch_bounds__(256)
void ln_k(const float* __restrict__ x, const float* __restrict__ gamma,
          const float* __restrict__ beta, ushort* __restrict__ out)
{
    const int wave = threadIdx.x >> 6;
    const int lane = threadIdx.x & 63;
    const size_t row = (size_t)blockIdx.x * 4 + wave;

    const float4 v = *(const float4*)(x + row * 256 + lane * 4);
    float s  = v.x + v.y + v.z + v.w;
    float s2 = v.x * v.x + v.y * v.y + v.z * v.z + v.w * v.w;
#pragma unroll
    for (int off = 32; off > 0; off >>= 1) {
        s  += __shfl_xor(s, off);
        s2 += __shfl_xor(s2, off);
    }
    const float mu  = s * (1.f / 256.f);
    const float var = s2 * (1.f / 256.f) - mu * mu;
    const float r   = rsqrtf(var + 1e-5f);

    const float4 g = *(const float4*)(gamma + lane * 4);
    const float4 b = *(const float4*)(beta + lane * 4);
    ushort4 o;
    o.x = f2b((v.x - mu) * r * g.x + b.x);
    o.y = f2b((v.y - mu) * r * g.y + b.y);
    o.z = f2b((v.z - mu) * r * g.z + b.z);
    o.w = f2b((v.w - mu) * r * g.w + b.w);
    *(ushort4*)(out + row * 256 + lane * 4) = o;
}

// ---------------------------------------------------------------------------
__global__ __launch_bounds__(256)
void f2b_k(const float* __restrict__ x, ushort* __restrict__ y, int n4)
{
    const int i = blockIdx.x * 256 + threadIdx.x;
    if (i < n4) {
        const float4 v = ((const float4*)x)[i];
        ushort4 o = { f2b(v.x), f2b(v.y), f2b(v.z), f2b(v.w) };
        ((ushort4*)y)[i] = o;
    }
}

// fp32 [K][N] -> bf16 [N][K] transpose-convert
__global__ __launch_bounds__(256)
void tconv_k(const float* __restrict__ w, ushort* __restrict__ wT, int K, int N)
{
    const int i = blockIdx.x * 256 + threadIdx.x;
    if (i < K * N) {
        const int k = i / N, n = i - k * N;
        wT[(size_t)n * K + k] = f2b(w[i]);
    }
}

// combined off|attn|zeros projection weight [384][128] bf16 + bias [384] f32
__global__ __launch_bounds__(256)
void prep_proj_k(const float* __restrict__ w_off, const float* __restrict__ b_off,
                 const float* __restrict__ w_attn, const float* __restrict__ b_attn,
                 ushort* __restrict__ wT, float* __restrict__ biasc)
{
    const int i = blockIdx.x * 256 + threadIdx.x;
    if (i < 384 * 128) {
        const int nn = i >> 7, k = i & 127;
        float v = 0.f;
        if (nn < 192)      v = w_off[(size_t)k * 192 + nn];
        else if (nn < 288) v = w_attn[(size_t)k * 96 + (nn - 192)];
        wT[i] = f2b(v);
    }
    if (i < 384) {
        float b = 0.f;
        if (i < 192)      b = b_off[i];
        else if (i < 288) b = b_attn[i - 192];
        biasc[i] = b;
    }
}

// ---------------------------------------------------------------------------
extern "C" void kernel_launch(void* const* d_in, const int* in_sizes, int n_in,
                              void* d_out, int out_size, void* d_ws, size_t ws_size,
                              hipStream_t stream)
{
    const float* src     = (const float*)d_in[0];
    const float* flow    = (const float*)d_in[1];
    const float* w_value = (const float*)d_in[4];
    const float* b_value = (const float*)d_in[5];
    const float* w_off   = (const float*)d_in[6];
    const float* b_off   = (const float*)d_in[7];
    const float* w_attn  = (const float*)d_in[8];
    const float* b_attn  = (const float*)d_in[9];
    const float* w_out   = (const float*)d_in[10];
    const float* b_out   = (const float*)d_in[11];
    const float* gamma   = (const float*)d_in[12];
    const float* beta    = (const float*)d_in[13];
    const float* w1      = (const float*)d_in[14];
    const float* b1      = (const float*)d_in[15];
    const float* w2      = (const float*)d_in[16];
    const float* b2      = (const float*)d_in[17];
    float* out = (float*)d_out;
    char*  wsb = (char*)d_ws;

    // Workspace (bytes), lifetime-aliased; total ~110.3 MB:
    //   [0, 22020096)            src_bf        (dead after value GEMM)
    //   [22020096, 30408704)     flow_bf       (dead after proj GEMM)
    //   [30408704, 47185920)     acc_bf        (steps sampler..out GEMM)
    //   [0, 67108864)            ffn1_bf       (written at FFN1, after above dead)
    //   [67108864, 89128960)     value_bf      (dead after sampler) -> ln_bf
    //   [89128960, 114294784)    projc_bf      (dead after sampler)
    //   [114294784, ...)         bf16 weights + proj bias
    ushort* src_bf   = (ushort*)(wsb);
    ushort* flow_bf  = (ushort*)(wsb + 22020096);
    ushort* acc_bf   = (ushort*)(wsb + 30408704);
    ushort* ffn1_bf  = (ushort*)(wsb);
    ushort* value_bf = (ushort*)(wsb + 67108864);
    ushort* ln_bf    = (ushort*)(wsb + 67108864);
    ushort* projc_bf = (ushort*)(wsb + 89128960);
    ushort* wvT      = (ushort*)(wsb + 114294784);
    ushort* woT      = (ushort*)(wsb + 114425856);
    ushort* w1T      = (ushort*)(wsb + 114556928);
    ushort* w2T      = (ushort*)(wsb + 115081216);
    ushort* wcT      = (ushort*)(wsb + 115605504);
    float*  biasc    = (float*) (wsb + 115703808);

    const int Mq = NB * LQ;     // 32768
    const int Mv = NB * LENIN;  // 43008

    // 0. dtype conversions / weight prep
    f2b_k<<<(Mv * 256 / 4 + 255) / 256, 256, 0, stream>>>(src, src_bf, Mv * 256 / 4);
    f2b_k<<<(Mq * 128 / 4 + 255) / 256, 256, 0, stream>>>(flow, flow_bf, Mq * 128 / 4);
    tconv_k<<<(256 * 256 + 255) / 256, 256, 0, stream>>>(w_value, wvT, 256, 256);
    tconv_k<<<(256 * 256 + 255) / 256, 256, 0, stream>>>(w_out,  woT, 256, 256);
    tconv_k<<<(256 * 1024 + 255) / 256, 256, 0, stream>>>(w1, w1T, 256, 1024);
    tconv_k<<<(1024 * 256 + 255) / 256, 256, 0, stream>>>(w2, w2T, 1024, 256);
    prep_proj_k<<<192, 256, 0, stream>>>(w_off, b_off, w_attn, b_attn, wcT, biasc);

    // 1. value = src @ w_value + b_value  [43008 x 256] bf16 out
    mfma_gemm<false, false, true><<<dim3(2, Mv / 128), 256, 0, stream>>>(
        src_bf, wvT, b_value, nullptr, value_bf, 256, 256);

    // 2. proj = flow @ [w_off|w_attn|0] + bias  [32768 x 384] bf16 out
    mfma_gemm<false, false, true><<<dim3(3, Mq / 128), 256, 0, stream>>>(
        flow_bf, wcT, biasc, nullptr, projc_bf, 384, 128);

    // 3. deformable sampling (fused softmax)  [32768 x 256] bf16 out
    sample_k<<<Mq / 8, 256, 0, stream>>>(value_bf, projc_bf, acc_bf);

    // 4. x = acc @ w_out + b_out -> d_out fp32
    mfma_gemm<false, false, false><<<dim3(2, Mq / 128), 256, 0, stream>>>(
        acc_bf, woT, b_out, nullptr, out, 256, 256);

    // 5. ln = LayerNorm(x) -> bf16
    ln_k<<<Mq / 4, 256, 0, stream>>>(out, gamma, beta, ln_bf);

    // 6. ffn1 = relu(ln @ w1 + b1) -> bf16  [32768 x 1024]
    mfma_gemm<true, false, true><<<dim3(8, Mq / 128), 256, 0, stream>>>(
        ln_bf, w1T, b1, nullptr, ffn1_bf, 1024, 256);

    // 7. out = x + ffn1 @ w2 + b2  [32768 x 256]
    mfma_gemm<false, true, false><<<dim3(2, Mq / 128), 256, 0, stream>>>(
        ffn1_bf, w2T, b2, out, out, 256, 1024);
}

// Round 6
// 308.780 us; speedup vs baseline: 3.2162x; 1.0108x over previous
//
#include <hip/hip_runtime.h>
#include <cstdint>
#include <cstddef>

#define D_MODEL  256
#define D_FLOW   128
#define D_FFN    1024
#define N_HEADS  8
#define N_LEVELS 3
#define N_POINTS 4
#define D_HEAD   32
#define LQ       16384
#define LENIN    21504
#define NB       2

typedef unsigned short ushort;
typedef __attribute__((ext_vector_type(8))) short bf16x8;   // 8 bf16 in 4 VGPRs
typedef __attribute__((ext_vector_type(4))) float f32x4;

__device__ __forceinline__ ushort f2b(float f) {            // fp32 -> bf16 RNE
    uint32_t u = __float_as_uint(f);
    uint32_t r = (u + 0x7fffu + ((u >> 16) & 1u)) >> 16;
    return (ushort)r;
}

// async 16B global->LDS copy; LDS dest = wave-uniform base + lane*16
__device__ __forceinline__ void gl_lds16(const void* g, void* l) {
    __builtin_amdgcn_global_load_lds(
        (const __attribute__((address_space(1))) unsigned int*)g,
        (__attribute__((address_space(3))) unsigned int*)l,
        16, 0, 0);
}

// ---------------------------------------------------------------------------
// bf16 MFMA GEMM: C[M,N] = A[M,K] @ B^T[N,K] + bias[N]  (B pre-transposed)
// BM=BN=128, BK=64, 256 thr = 4 waves (2x2), 4x4 16x16x32 MFMA tiles/wave,
// 2 MFMA k-steps per staged tile (32 MFMA / barrier-pair).
// LDS [128][64] bf16 unpadded; logical k-chunk c stored at physical chunk
// p = c ^ (row & 7)  (both the staging source address and the ds_read_b128
// offset apply the same XOR -> conflict-free with wave-uniform-base LDS DMA).
// A_FP32: A is fp32, converted to bf16 during explicit staging (saves the
// separate f2b pass). Requires M%128==0, N%128==0, K%64==0.
// ---------------------------------------------------------------------------
template<bool A_FP32, bool RELU, bool RESID, bool OUT_BF16>
__global__ __launch_bounds__(256)
void mfma_gemm(const void* __restrict__ Ain, const ushort* __restrict__ Bt,
               const float* __restrict__ bias, const float* __restrict__ resid,
               void* __restrict__ Cout, int N, int K)
{
    __shared__ ushort As[128 * 64];   // 16 KB
    __shared__ ushort Bs[128 * 64];   // 16 KB

    const int tid  = threadIdx.x;
    const int wave = tid >> 6;
    const int lane = tid & 63;
    const int quad = lane >> 4;
    const int l16  = lane & 15;
    const int wr   = (wave >> 1) * 64;
    const int wc   = (wave & 1) * 64;
    const int bm   = blockIdx.y * 128;
    const int bn   = blockIdx.x * 128;

    // staging: each wave stages 32 rows per matrix, 4 issues x 8 rows.
    // lane -> row-in-group sr = lane>>3, physical chunk sc = lane&7 (16B).
    const int sr  = lane >> 3;
    const int sc  = lane & 7;
    const int gch = sc ^ sr;          // logical source chunk (row&7 == sr)

    f32x4 acc[4][4] = {};
    const int swz = l16 & 7;

    for (int k0 = 0; k0 < K; k0 += 64) {
        __syncthreads();               // prior iteration's ds_reads done
        if (A_FP32) {
            const float* Af = (const float*)Ain;
#pragma unroll
            for (int i = 0; i < 4; ++i) {
                const int row = wave * 32 + i * 8 + sr;
                const float* p = Af + (size_t)(bm + row) * K + k0 + gch * 8;
                const float4 v0 = *(const float4*)(p);
                const float4 v1 = *(const float4*)(p + 4);
                bf16x8 pk;
                pk[0] = (short)f2b(v0.x); pk[1] = (short)f2b(v0.y);
                pk[2] = (short)f2b(v0.z); pk[3] = (short)f2b(v0.w);
                pk[4] = (short)f2b(v1.x); pk[5] = (short)f2b(v1.y);
                pk[6] = (short)f2b(v1.z); pk[7] = (short)f2b(v1.w);
                *(bf16x8*)&As[(size_t)row * 64 + sc * 8] = pk;
            }
        } else {
            const ushort* Ab = (const ushort*)Ain;
#pragma unroll
            for (int i = 0; i < 4; ++i) {
                const int row = wave * 32 + i * 8;
                gl_lds16(Ab + (size_t)(bm + row + sr) * K + k0 + gch * 8,
                         As + (size_t)row * 64);
            }
        }
#pragma unroll
        for (int i = 0; i < 4; ++i) {
            const int row = wave * 32 + i * 8;
            gl_lds16(Bt + (size_t)(bn + row + sr) * K + k0 + gch * 8,
                     Bs + (size_t)row * 64);
        }
        __syncthreads();               // drains vmcnt/lgkm: tile resident

#pragma unroll
        for (int kk = 0; kk < 2; ++kk) {
            bf16x8 af[4], bfr[4];
#pragma unroll
            for (int mi = 0; mi < 4; ++mi) {
                const int p = (kk * 4 + quad) ^ swz;
                af[mi] = *(const bf16x8*)&As[(wr + mi * 16 + l16) * 64 + p * 8];
            }
#pragma unroll
            for (int ni = 0; ni < 4; ++ni) {
                const int p = (kk * 4 + quad) ^ swz;
                bfr[ni] = *(const bf16x8*)&Bs[(wc + ni * 16 + l16) * 64 + p * 8];
            }
#pragma unroll
            for (int mi = 0; mi < 4; ++mi)
#pragma unroll
                for (int ni = 0; ni < 4; ++ni)
                    acc[mi][ni] = __builtin_amdgcn_mfma_f32_16x16x32_bf16(
                        af[mi], bfr[ni], acc[mi][ni], 0, 0, 0);
        }
    }

#pragma unroll
    for (int mi = 0; mi < 4; ++mi) {
#pragma unroll
        for (int ni = 0; ni < 4; ++ni) {
            const int col = bn + wc + ni * 16 + l16;
            const float bb = bias[col];
#pragma unroll
            for (int r = 0; r < 4; ++r) {
                const int row = bm + wr + mi * 16 + quad * 4 + r;
                const size_t idx = (size_t)row * N + col;
                float c = acc[mi][ni][r] + bb;
                if (RELU)  c = fmaxf(c, 0.f);
                if (RESID) c += resid[idx];
                if (OUT_BF16) ((ushort*)Cout)[idx] = f2b(c);
                else          ((float*)Cout)[idx]  = c;
            }
        }
    }
}

// ---------------------------------------------------------------------------
// Fused softmax + deformable bilinear sampling. value in bf16.
// Block = 256 thr = 4 waves; 2 queries per wave (32 lanes each):
// lane -> qh = lane>>5, h = (lane>>2)&7, cg = lane&3 (8 bf16 channels).
// Co-limited VALU (~73%) + L2 (~17 TB/s of 34.5) at 47 us — near floor.
// ---------------------------------------------------------------------------
__device__ __forceinline__ void acc8(float* a, uint4 g, float w) {
    a[0] = fmaf(w, __uint_as_float(g.x << 16), a[0]);
    a[1] = fmaf(w, __uint_as_float(g.x & 0xffff0000u), a[1]);
    a[2] = fmaf(w, __uint_as_float(g.y << 16), a[2]);
    a[3] = fmaf(w, __uint_as_float(g.y & 0xffff0000u), a[3]);
    a[4] = fmaf(w, __uint_as_float(g.z << 16), a[4]);
    a[5] = fmaf(w, __uint_as_float(g.z & 0xffff0000u), a[5]);
    a[6] = fmaf(w, __uint_as_float(g.w << 16), a[6]);
    a[7] = fmaf(w, __uint_as_float(g.w & 0xffff0000u), a[7]);
}

__global__ __launch_bounds__(256)
void sample_k(const ushort* __restrict__ value, const ushort* __restrict__ projc,
              ushort* __restrict__ acc)
{
    __shared__ float sOff[8][192];
    __shared__ float sAttn[8][96];

    const int tid = threadIdx.x;
    const int bq0 = blockIdx.x * 8;

    for (int i = tid; i < 8 * 288; i += 256) {
        const int qw = i / 288, j = i - qw * 288;
        const float v = __uint_as_float((uint32_t)projc[(size_t)(bq0 + qw) * 384 + j] << 16);
        if (j < 192) sOff[qw][j] = v;
        else         sAttn[qw][j - 192] = v;
    }
    __syncthreads();

    if (tid < 64) {                        // 8 queries x 8 heads: softmax(12)
        const int qw = tid >> 3, h = tid & 7;
        float* row = &sAttn[qw][h * 12];
        float m = row[0];
#pragma unroll
        for (int j = 1; j < 12; ++j) m = fmaxf(m, row[j]);
        float s = 0.f;
#pragma unroll
        for (int j = 0; j < 12; ++j) { const float e = __expf(row[j] - m); row[j] = e; s += e; }
        const float inv = 1.f / s;
#pragma unroll
        for (int j = 0; j < 12; ++j) row[j] *= inv;
    }
    __syncthreads();

    const int wave = tid >> 6, lane = tid & 63;
    const int qh = lane >> 5;
    const int h  = (lane >> 2) & 7;
    const int cg = lane & 3;
    const int qw = wave * 2 + qh;
    const int bq = bq0 + qw;
    const int n  = bq >> 14;
    const int q  = bq & 16383;

    const float qx = (float)(q & 127) + 0.5f;
    const float qy = (float)(q >> 7) + 0.5f;

    const int LSIc[3] = {0, 16384, 20480};

    float a[8] = {0.f, 0.f, 0.f, 0.f, 0.f, 0.f, 0.f, 0.f};
    const ushort* vbase = value + (size_t)n * LENIN * D_MODEL + h * D_HEAD + cg * 8;

#pragma unroll
    for (int l = 0; l < N_LEVELS; ++l) {
        const int   W     = 128 >> l;
        const int   SH    = 7 - l;
        const float scale = 1.f / (float)(1 << l);
        const float cx    = qx * scale - 0.5f;
        const float cy    = qy * scale - 0.5f;
        const ushort* vlev = vbase + ((size_t)LSIc[l] << 8);
#pragma unroll
        for (int p = 0; p < N_POINTS; ++p) {
            const int ob = (h * N_LEVELS + l) * (N_POINTS * 2) + p * 2;
            const float aw = sAttn[qw][h * 12 + l * 4 + p];
            const float x = cx + sOff[qw][ob];
            const float y = cy + sOff[qw][ob + 1];
            const float x0f = floorf(x), y0f = floorf(y);
            const int x0 = (int)x0f, y0 = (int)y0f;
            const float dx = x - x0f, dy = y - y0f;
            float wx1 = dx * aw, wx0 = aw - wx1;
            float wy1 = dy,      wy0 = 1.f - dy;
            if ((unsigned)x0       > (unsigned)(W - 1)) wx0 = 0.f;
            if ((unsigned)(x0 + 1) > (unsigned)(W - 1)) wx1 = 0.f;
            if ((unsigned)y0       > (unsigned)(W - 1)) wy0 = 0.f;
            if ((unsigned)(y0 + 1) > (unsigned)(W - 1)) wy1 = 0.f;
            const int xi0 = min(max(x0, 0), W - 1);
            const int xi1 = min(max(x0 + 1, 0), W - 1);
            const int yi0 = min(max(y0, 0), W - 1);
            const int yi1 = min(max(y0 + 1, 0), W - 1);
            const uint4 g00 = *(const uint4*)(vlev + ((size_t)((yi0 << SH) + xi0) << 8));
            const uint4 g01 = *(const uint4*)(vlev + ((size_t)((yi0 << SH) + xi1) << 8));
            const uint4 g10 = *(const uint4*)(vlev + ((size_t)((yi1 << SH) + xi0) << 8));
            const uint4 g11 = *(const uint4*)(vlev + ((size_t)((yi1 << SH) + xi1) << 8));
            acc8(a, g00, wx0 * wy0);
            acc8(a, g01, wx1 * wy0);
            acc8(a, g10, wx0 * wy1);
            acc8(a, g11, wx1 * wy1);
        }
    }

    const uint32_t o0 = (uint32_t)f2b(a[0]) | ((uint32_t)f2b(a[1]) << 16);
    const uint32_t o1 = (uint32_t)f2b(a[2]) | ((uint32_t)f2b(a[3]) << 16);
    const uint32_t o2 = (uint32_t)f2b(a[4]) | ((uint32_t)f2b(a[5]) << 16);
    const uint32_t o3 = (uint32_t)f2b(a[6]) | ((uint32_t)f2b(a[7]) << 16);
    const uint4 ov = {o0, o1, o2, o3};
    *(uint4*)(acc + (size_t)bq * D_MODEL + h * D_HEAD + cg * 8) = ov;
}

// ---------------------------------------------------------------------------
// LayerNorm over 256, fp32 in -> bf16 out.
// ---------------------------------------------------------------------------
__global__ __launch_bounds__(256)
void ln_k(const float* __restrict__ x, const float* __restrict__ gamma,
          const float* __restrict__ beta, ushort* __restrict__ out)
{
    const int wave = threadIdx.x >> 6;
    const int lane = threadIdx.x & 63;
    const size_t row = (size_t)blockIdx.x * 4 + wave;

    const float4 v = *(const float4*)(x + row * 256 + lane * 4);
    float s  = v.x + v.y + v.z + v.w;
    float s2 = v.x * v.x + v.y * v.y + v.z * v.z + v.w * v.w;
#pragma unroll
    for (int off = 32; off > 0; off >>= 1) {
        s  += __shfl_xor(s, off);
        s2 += __shfl_xor(s2, off);
    }
    const float mu  = s * (1.f / 256.f);
    const float var = s2 * (1.f / 256.f) - mu * mu;
    const float r   = rsqrtf(var + 1e-5f);

    const float4 g = *(const float4*)(gamma + lane * 4);
    const float4 b = *(const float4*)(beta + lane * 4);
    ushort4 o;
    o.x = f2b((v.x - mu) * r * g.x + b.x);
    o.y = f2b((v.y - mu) * r * g.y + b.y);
    o.z = f2b((v.z - mu) * r * g.z + b.z);
    o.w = f2b((v.w - mu) * r * g.w + b.w);
    *(ushort4*)(out + row * 256 + lane * 4) = o;
}

// fp32 [K][N] -> bf16 [N][K] transpose-convert
__global__ __launch_bounds__(256)
void tconv_k(const float* __restrict__ w, ushort* __restrict__ wT, int K, int N)
{
    const int i = blockIdx.x * 256 + threadIdx.x;
    if (i < K * N) {
        const int k = i / N, n = i - k * N;
        wT[(size_t)n * K + k] = f2b(w[i]);
    }
}

// combined off|attn|zeros projection weight [384][128] bf16 + bias [384] f32
__global__ __launch_bounds__(256)
void prep_proj_k(const float* __restrict__ w_off, const float* __restrict__ b_off,
                 const float* __restrict__ w_attn, const float* __restrict__ b_attn,
                 ushort* __restrict__ wT, float* __restrict__ biasc)
{
    const int i = blockIdx.x * 256 + threadIdx.x;
    if (i < 384 * 128) {
        const int nn = i >> 7, k = i & 127;
        float v = 0.f;
        if (nn < 192)      v = w_off[(size_t)k * 192 + nn];
        else if (nn < 288) v = w_attn[(size_t)k * 96 + (nn - 192)];
        wT[i] = f2b(v);
    }
    if (i < 384) {
        float b = 0.f;
        if (i < 192)      b = b_off[i];
        else if (i < 288) b = b_attn[i - 192];
        biasc[i] = b;
    }
}

// ---------------------------------------------------------------------------
extern "C" void kernel_launch(void* const* d_in, const int* in_sizes, int n_in,
                              void* d_out, int out_size, void* d_ws, size_t ws_size,
                              hipStream_t stream)
{
    const float* src     = (const float*)d_in[0];
    const float* flow    = (const float*)d_in[1];
    const float* w_value = (const float*)d_in[4];
    const float* b_value = (const float*)d_in[5];
    const float* w_off   = (const float*)d_in[6];
    const float* b_off   = (const float*)d_in[7];
    const float* w_attn  = (const float*)d_in[8];
    const float* b_attn  = (const float*)d_in[9];
    const float* w_out   = (const float*)d_in[10];
    const float* b_out   = (const float*)d_in[11];
    const float* gamma   = (const float*)d_in[12];
    const float* beta    = (const float*)d_in[13];
    const float* w1      = (const float*)d_in[14];
    const float* b1      = (const float*)d_in[15];
    const float* w2      = (const float*)d_in[16];
    const float* b2      = (const float*)d_in[17];
    float* out = (float*)d_out;
    char*  wsb = (char*)d_ws;

    // Workspace (bytes), lifetime-aliased; total ~93.7 MB:
    //   [0, 67108864)           ffn1_bf (written step 6); earlier holds:
    //       value_bf @ 0          (22,020,096)  dead after sampler
    //       acc_bf   @ 22020096   (16,777,216)  dead after out GEMM
    //   [67108864, 92274688)    projc_bf (dead after sampler) -> ln_bf
    //   [92274688, ...)         bf16 weights + proj bias
    ushort* ffn1_bf  = (ushort*)(wsb);
    ushort* value_bf = (ushort*)(wsb);
    ushort* acc_bf   = (ushort*)(wsb + 22020096);
    ushort* projc_bf = (ushort*)(wsb + 67108864);
    ushort* ln_bf    = (ushort*)(wsb + 67108864);
    ushort* wvT      = (ushort*)(wsb + 92274688);
    ushort* woT      = (ushort*)(wsb + 92405760);
    ushort* w1T      = (ushort*)(wsb + 92536832);
    ushort* w2T      = (ushort*)(wsb + 93061120);
    ushort* wcT      = (ushort*)(wsb + 93585408);
    float*  biasc    = (float*) (wsb + 93683712);

    const int Mq = NB * LQ;     // 32768
    const int Mv = NB * LENIN;  // 43008

    // 0. weight prep (bf16 transposed)
    tconv_k<<<(256 * 256 + 255) / 256, 256, 0, stream>>>(w_value, wvT, 256, 256);
    tconv_k<<<(256 * 256 + 255) / 256, 256, 0, stream>>>(w_out,  woT, 256, 256);
    tconv_k<<<(256 * 1024 + 255) / 256, 256, 0, stream>>>(w1, w1T, 256, 1024);
    tconv_k<<<(1024 * 256 + 255) / 256, 256, 0, stream>>>(w2, w2T, 1024, 256);
    prep_proj_k<<<192, 256, 0, stream>>>(w_off, b_off, w_attn, b_attn, wcT, biasc);

    // 1. value = src @ w_value + b_value  [43008 x 256] (fp32 A staged) bf16 out
    mfma_gemm<true, false, false, true><<<dim3(2, Mv / 128), 256, 0, stream>>>(
        src, wvT, b_value, nullptr, value_bf, 256, 256);

    // 2. proj = flow @ [w_off|w_attn|0] + bias  [32768 x 384] (fp32 A) bf16 out
    mfma_gemm<true, false, false, true><<<dim3(3, Mq / 128), 256, 0, stream>>>(
        flow, wcT, biasc, nullptr, projc_bf, 384, 128);

    // 3. deformable sampling (fused softmax)  [32768 x 256] bf16 out
    sample_k<<<Mq / 8, 256, 0, stream>>>(value_bf, projc_bf, acc_bf);

    // 4. x = acc @ w_out + b_out -> d_out fp32
    mfma_gemm<false, false, false, false><<<dim3(2, Mq / 128), 256, 0, stream>>>(
        acc_bf, woT, b_out, nullptr, out, 256, 256);

    // 5. ln = LayerNorm(x) -> bf16
    ln_k<<<Mq / 4, 256, 0, stream>>>(out, gamma, beta, ln_bf);

    // 6. ffn1 = relu(ln @ w1 + b1) -> bf16  [32768 x 1024]
    mfma_gemm<false, true, false, true><<<dim3(8, Mq / 128), 256, 0, stream>>>(
        ln_bf, w1T, b1, nullptr, ffn1_bf, 1024, 256);

    // 7. out = x + ffn1 @ w2 + b2  [32768 x 256]
    mfma_gemm<false, false, true, false><<<dim3(2, Mq / 128), 256, 0, stream>>>(
        ffn1_bf, w2T, b2, out, out, 256, 1024);
}

// Round 7
// 292.126 us; speedup vs baseline: 3.3995x; 1.0570x over previous
//
#include <hip/hip_runtime.h>
#include <cstdint>
#include <cstddef>

#define D_MODEL  256
#define D_FLOW   128
#define D_FFN    1024
#define N_HEADS  8
#define N_LEVELS 3
#define N_POINTS 4
#define D_HEAD   32
#define LQ       16384
#define LENIN    21504
#define NB       2

typedef unsigned short ushort;
typedef __attribute__((ext_vector_type(8))) short bf16x8;   // 8 bf16 in 4 VGPRs
typedef __attribute__((ext_vector_type(4))) float f32x4;

__device__ __forceinline__ ushort f2b(float f) {            // fp32 -> bf16 RNE
    uint32_t u = __float_as_uint(f);
    uint32_t r = (u + 0x7fffu + ((u >> 16) & 1u)) >> 16;
    return (ushort)r;
}

// async 16B global->LDS copy; LDS dest = wave-uniform base + lane*16
__device__ __forceinline__ void gl_lds16(const void* g, void* l) {
    __builtin_amdgcn_global_load_lds(
        (const __attribute__((address_space(1))) unsigned int*)g,
        (__attribute__((address_space(3))) unsigned int*)l,
        16, 0, 0);
}

// ---------------------------------------------------------------------------
// bf16 MFMA GEMM (round-6 structure, kept at its plateau): BM=BN=128, BK=64.
// ---------------------------------------------------------------------------
template<bool A_FP32, bool RELU, bool RESID, bool OUT_BF16>
__global__ __launch_bounds__(256)
void mfma_gemm(const void* __restrict__ Ain, const ushort* __restrict__ Bt,
               const float* __restrict__ bias, const float* __restrict__ resid,
               void* __restrict__ Cout, int N, int K)
{
    __shared__ ushort As[128 * 64];   // 16 KB
    __shared__ ushort Bs[128 * 64];   // 16 KB

    const int tid  = threadIdx.x;
    const int wave = tid >> 6;
    const int lane = tid & 63;
    const int quad = lane >> 4;
    const int l16  = lane & 15;
    const int wr   = (wave >> 1) * 64;
    const int wc   = (wave & 1) * 64;
    const int bm   = blockIdx.y * 128;
    const int bn   = blockIdx.x * 128;

    const int sr  = lane >> 3;
    const int sc  = lane & 7;
    const int gch = sc ^ sr;

    f32x4 acc[4][4] = {};
    const int swz = l16 & 7;

    for (int k0 = 0; k0 < K; k0 += 64) {
        __syncthreads();
        if (A_FP32) {
            const float* Af = (const float*)Ain;
#pragma unroll
            for (int i = 0; i < 4; ++i) {
                const int row = wave * 32 + i * 8 + sr;
                const float* p = Af + (size_t)(bm + row) * K + k0 + gch * 8;
                const float4 v0 = *(const float4*)(p);
                const float4 v1 = *(const float4*)(p + 4);
                bf16x8 pk;
                pk[0] = (short)f2b(v0.x); pk[1] = (short)f2b(v0.y);
                pk[2] = (short)f2b(v0.z); pk[3] = (short)f2b(v0.w);
                pk[4] = (short)f2b(v1.x); pk[5] = (short)f2b(v1.y);
                pk[6] = (short)f2b(v1.z); pk[7] = (short)f2b(v1.w);
                *(bf16x8*)&As[(size_t)row * 64 + sc * 8] = pk;
            }
        } else {
            const ushort* Ab = (const ushort*)Ain;
#pragma unroll
            for (int i = 0; i < 4; ++i) {
                const int row = wave * 32 + i * 8;
                gl_lds16(Ab + (size_t)(bm + row + sr) * K + k0 + gch * 8,
                         As + (size_t)row * 64);
            }
        }
#pragma unroll
        for (int i = 0; i < 4; ++i) {
            const int row = wave * 32 + i * 8;
            gl_lds16(Bt + (size_t)(bn + row + sr) * K + k0 + gch * 8,
                     Bs + (size_t)row * 64);
        }
        __syncthreads();

#pragma unroll
        for (int kk = 0; kk < 2; ++kk) {
            bf16x8 af[4], bfr[4];
#pragma unroll
            for (int mi = 0; mi < 4; ++mi) {
                const int p = (kk * 4 + quad) ^ swz;
                af[mi] = *(const bf16x8*)&As[(wr + mi * 16 + l16) * 64 + p * 8];
            }
#pragma unroll
            for (int ni = 0; ni < 4; ++ni) {
                const int p = (kk * 4 + quad) ^ swz;
                bfr[ni] = *(const bf16x8*)&Bs[(wc + ni * 16 + l16) * 64 + p * 8];
            }
#pragma unroll
            for (int mi = 0; mi < 4; ++mi)
#pragma unroll
                for (int ni = 0; ni < 4; ++ni)
                    acc[mi][ni] = __builtin_amdgcn_mfma_f32_16x16x32_bf16(
                        af[mi], bfr[ni], acc[mi][ni], 0, 0, 0);
        }
    }

#pragma unroll
    for (int mi = 0; mi < 4; ++mi) {
#pragma unroll
        for (int ni = 0; ni < 4; ++ni) {
            const int col = bn + wc + ni * 16 + l16;
            const float bb = bias[col];
#pragma unroll
            for (int r = 0; r < 4; ++r) {
                const int row = bm + wr + mi * 16 + quad * 4 + r;
                const size_t idx = (size_t)row * N + col;
                float c = acc[mi][ni][r] + bb;
                if (RELU)  c = fmaxf(c, 0.f);
                if (RESID) c += resid[idx];
                if (OUT_BF16) ((ushort*)Cout)[idx] = f2b(c);
                else          ((float*)Cout)[idx]  = c;
            }
        }
    }
}

// ---------------------------------------------------------------------------
// Fused out-projection GEMM + LayerNorm.
// BM=64, BN=256 (full row per block -> LN possible), BK=32, 256 thr.
// Waves 2x2: wr=(wave>>1)*32 (2 m-tiles of 16), wc=(wave&1)*128 (8 n-tiles).
// Emits x (fp32, residual source) and ln (bf16, FFN1 input).
// ---------------------------------------------------------------------------
__global__ __launch_bounds__(256)
void gemm_ln_k(const ushort* __restrict__ A, const ushort* __restrict__ Bt,
               const float* __restrict__ bias, const float* __restrict__ gamma,
               const float* __restrict__ beta,
               float* __restrict__ xout, ushort* __restrict__ lnout, int K)
{
    __shared__ ushort As[64 * 32];      // 4 KB
    __shared__ ushort Bs[256 * 32];     // 16 KB
    __shared__ float  sS[64][33];       // +1 pad: slot-major stores conflict-free
    __shared__ float  sS2[64][33];
    __shared__ float  sMu[64], sRi[64];

    const int tid  = threadIdx.x;
    const int wave = tid >> 6;
    const int lane = tid & 63;
    const int quad = lane >> 4;
    const int l16  = lane & 15;
    const int wr   = (wave >> 1) * 32;
    const int wc   = (wave & 1) * 128;
    const int bm   = blockIdx.x * 64;

    const int sr  = lane >> 2;          // 0..15
    const int sc  = lane & 3;
    const int gch = sc ^ (sr & 3);

    f32x4 acc[2][8] = {};
    const int swz = l16 & 3;

    for (int k0 = 0; k0 < K; k0 += 32) {
        __syncthreads();
        gl_lds16(A + (size_t)(bm + wave * 16 + sr) * K + k0 + gch * 8,
                 As + wave * 16 * 32);
#pragma unroll
        for (int i = 0; i < 4; ++i) {
            const int row = wave * 64 + i * 16;
            gl_lds16(Bt + (size_t)(row + sr) * K + k0 + gch * 8,
                     Bs + (size_t)row * 32);
        }
        __syncthreads();

        bf16x8 af[2], bfr[8];
#pragma unroll
        for (int mi = 0; mi < 2; ++mi)
            af[mi] = *(const bf16x8*)&As[(wr + mi * 16 + l16) * 32 + ((quad ^ swz) << 3)];
#pragma unroll
        for (int ni = 0; ni < 8; ++ni)
            bfr[ni] = *(const bf16x8*)&Bs[(wc + ni * 16 + l16) * 32 + ((quad ^ swz) << 3)];
#pragma unroll
        for (int mi = 0; mi < 2; ++mi)
#pragma unroll
            for (int ni = 0; ni < 8; ++ni)
                acc[mi][ni] = __builtin_amdgcn_mfma_f32_16x16x32_bf16(
                    af[mi], bfr[ni], acc[mi][ni], 0, 0, 0);
    }

    float bias8[8], g8[8], b8[8];
#pragma unroll
    for (int ni = 0; ni < 8; ++ni) {
        const int col = wc + ni * 16 + l16;
        bias8[ni] = bias[col];
        g8[ni]    = gamma[col];
        b8[ni]    = beta[col];
    }

    // per-(row) partial sums over this lane's 8 columns
#pragma unroll
    for (int mi = 0; mi < 2; ++mi)
#pragma unroll
        for (int r = 0; r < 4; ++r) {
            float s = 0.f, s2 = 0.f;
#pragma unroll
            for (int ni = 0; ni < 8; ++ni) {
                const float c = acc[mi][ni][r] + bias8[ni];
                s += c; s2 += c * c;
            }
            const int row = wr + mi * 16 + quad * 4 + r;
            sS[row][(wave & 1) * 16 + l16]  = s;
            sS2[row][(wave & 1) * 16 + l16] = s2;
        }
    __syncthreads();

    if (tid < 64) {
        float s = 0.f, s2 = 0.f;
#pragma unroll
        for (int j = 0; j < 32; ++j) { s += sS[tid][j]; s2 += sS2[tid][j]; }
        const float mu  = s * (1.f / 256.f);
        const float var = s2 * (1.f / 256.f) - mu * mu;
        sMu[tid] = mu;
        sRi[tid] = rsqrtf(var + 1e-5f);
    }
    __syncthreads();

#pragma unroll
    for (int mi = 0; mi < 2; ++mi)
#pragma unroll
        for (int r = 0; r < 4; ++r) {
            const int lrow = wr + mi * 16 + quad * 4 + r;
            const int grow = bm + lrow;
            const float mu = sMu[lrow], ri = sRi[lrow];
#pragma unroll
            for (int ni = 0; ni < 8; ++ni) {
                const int col = wc + ni * 16 + l16;
                const float c = acc[mi][ni][r] + bias8[ni];
                xout[(size_t)grow * 256 + col]  = c;
                lnout[(size_t)grow * 256 + col] = f2b((c - mu) * ri * g8[ni] + b8[ni]);
            }
        }
}

// ---------------------------------------------------------------------------
// Fused softmax + deformable bilinear sampling. value bf16.
// 2 queries/wave; lane -> qh=lane>>5, h=(lane>>2)&7, cg=lane&3 (8 channels).
// Odd channels fma directly on the raw u32 (bf16 high half + neighbor-bit
// mantissa tail, <2^-9 rel — below bf16 noise) — saves 4 v_and per corner.
// blockIdx XCD-stripe swizzle: each XCD serves one contiguous query stripe
// so its L2 holds a ~2.8 MB value slice instead of thrashing all 22 MB.
// ---------------------------------------------------------------------------
__device__ __forceinline__ void acc8(float* a, uint4 g, float w) {
    a[0] = fmaf(w, __uint_as_float(g.x << 16), a[0]);
    a[1] = fmaf(w, __uint_as_float(g.x), a[1]);
    a[2] = fmaf(w, __uint_as_float(g.y << 16), a[2]);
    a[3] = fmaf(w, __uint_as_float(g.y), a[3]);
    a[4] = fmaf(w, __uint_as_float(g.z << 16), a[4]);
    a[5] = fmaf(w, __uint_as_float(g.z), a[5]);
    a[6] = fmaf(w, __uint_as_float(g.w << 16), a[6]);
    a[7] = fmaf(w, __uint_as_float(g.w), a[7]);
}

__global__ __launch_bounds__(256)
void sample_k(const ushort* __restrict__ value, const ushort* __restrict__ projc,
              ushort* __restrict__ acc)
{
    __shared__ float sOff[8][192];
    __shared__ float sAttn[8][96];

    const int tid = threadIdx.x;
    const int bid = blockIdx.x;                       // 0..4095
    const int bq0 = (((bid & 7) << 9) | (bid >> 3)) << 3;   // XCD stripe swizzle

    for (int i = tid; i < 8 * 288; i += 256) {
        const int qw = i / 288, j = i - qw * 288;
        const float v = __uint_as_float((uint32_t)projc[(size_t)(bq0 + qw) * 384 + j] << 16);
        if (j < 192) sOff[qw][j] = v;
        else         sAttn[qw][j - 192] = v;
    }
    __syncthreads();

    if (tid < 64) {
        const int qw = tid >> 3, h = tid & 7;
        float* row = &sAttn[qw][h * 12];
        float m = row[0];
#pragma unroll
        for (int j = 1; j < 12; ++j) m = fmaxf(m, row[j]);
        float s = 0.f;
#pragma unroll
        for (int j = 0; j < 12; ++j) { const float e = __expf(row[j] - m); row[j] = e; s += e; }
        const float inv = 1.f / s;
#pragma unroll
        for (int j = 0; j < 12; ++j) row[j] *= inv;
    }
    __syncthreads();

    const int wave = tid >> 6, lane = tid & 63;
    const int qh = lane >> 5;
    const int h  = (lane >> 2) & 7;
    const int cg = lane & 3;
    const int qw = wave * 2 + qh;
    const int bq = bq0 + qw;
    const int n  = bq >> 14;
    const int q  = bq & 16383;

    const float qx = (float)(q & 127) + 0.5f;
    const float qy = (float)(q >> 7) + 0.5f;

    const int LSIc[3] = {0, 16384, 20480};

    float a[8] = {0.f, 0.f, 0.f, 0.f, 0.f, 0.f, 0.f, 0.f};
    const ushort* vbase = value + (size_t)n * LENIN * D_MODEL + h * D_HEAD + cg * 8;

#pragma unroll
    for (int l = 0; l < N_LEVELS; ++l) {
        const int   W     = 128 >> l;
        const int   SH    = 7 - l;
        const float scale = 1.f / (float)(1 << l);
        const float cx    = qx * scale - 0.5f;
        const float cy    = qy * scale - 0.5f;
        const ushort* vlev = vbase + ((size_t)LSIc[l] << 8);
#pragma unroll
        for (int p = 0; p < N_POINTS; ++p) {
            const int ob = (h * N_LEVELS + l) * (N_POINTS * 2) + p * 2;
            const float aw = sAttn[qw][h * 12 + l * 4 + p];
            const float x = cx + sOff[qw][ob];
            const float y = cy + sOff[qw][ob + 1];
            const float x0f = floorf(x), y0f = floorf(y);
            const int x0 = (int)x0f, y0 = (int)y0f;
            const float dx = x - x0f, dy = y - y0f;
            float wx1 = dx * aw, wx0 = aw - wx1;
            float wy1 = dy,      wy0 = 1.f - dy;
            if ((unsigned)x0       > (unsigned)(W - 1)) wx0 = 0.f;
            if ((unsigned)(x0 + 1) > (unsigned)(W - 1)) wx1 = 0.f;
            if ((unsigned)y0       > (unsigned)(W - 1)) wy0 = 0.f;
            if ((unsigned)(y0 + 1) > (unsigned)(W - 1)) wy1 = 0.f;
            const int xi0 = min(max(x0, 0), W - 1);
            const int xi1 = min(max(x0 + 1, 0), W - 1);
            const int yi0 = min(max(y0, 0), W - 1);
            const int yi1 = min(max(y0 + 1, 0), W - 1);
            const uint4 g00 = *(const uint4*)(vlev + ((size_t)((yi0 << SH) + xi0) << 8));
            const uint4 g01 = *(const uint4*)(vlev + ((size_t)((yi0 << SH) + xi1) << 8));
            const uint4 g10 = *(const uint4*)(vlev + ((size_t)((yi1 << SH) + xi0) << 8));
            const uint4 g11 = *(const uint4*)(vlev + ((size_t)((yi1 << SH) + xi1) << 8));
            acc8(a, g00, wx0 * wy0);
            acc8(a, g01, wx1 * wy0);
            acc8(a, g10, wx0 * wy1);
            acc8(a, g11, wx1 * wy1);
        }
    }

    const uint32_t o0 = (uint32_t)f2b(a[0]) | ((uint32_t)f2b(a[1]) << 16);
    const uint32_t o1 = (uint32_t)f2b(a[2]) | ((uint32_t)f2b(a[3]) << 16);
    const uint32_t o2 = (uint32_t)f2b(a[4]) | ((uint32_t)f2b(a[5]) << 16);
    const uint32_t o3 = (uint32_t)f2b(a[6]) | ((uint32_t)f2b(a[7]) << 16);
    const uint4 ov = {o0, o1, o2, o3};
    *(uint4*)(acc + (size_t)bq * D_MODEL + h * D_HEAD + cg * 8) = ov;
}

// ---------------------------------------------------------------------------
// All weight prep in one launch: 4 transpose-converts + combined proj weight.
// Index space: 65536 | 65536 | 262144 | 262144 | 49152 | 384 = 704,896.
// ---------------------------------------------------------------------------
__global__ __launch_bounds__(256)
void prep_all_k(const float* __restrict__ w_value, const float* __restrict__ w_out,
                const float* __restrict__ w1, const float* __restrict__ w2,
                const float* __restrict__ w_off, const float* __restrict__ b_off,
                const float* __restrict__ w_attn, const float* __restrict__ b_attn,
                ushort* __restrict__ wvT, ushort* __restrict__ woT,
                ushort* __restrict__ w1T, ushort* __restrict__ w2T,
                ushort* __restrict__ wcT, float* __restrict__ biasc)
{
    int i = blockIdx.x * 256 + threadIdx.x;
    if (i < 65536) {                                  // w_value [256][256] -> [n][k]
        const int k = i >> 8, n = i & 255;
        wvT[(size_t)n * 256 + k] = f2b(w_value[i]);
        return;
    }
    i -= 65536;
    if (i < 65536) {                                  // w_out [256][256]
        const int k = i >> 8, n = i & 255;
        woT[(size_t)n * 256 + k] = f2b(w_out[i]);
        return;
    }
    i -= 65536;
    if (i < 262144) {                                 // w1 [256][1024] -> [1024][256]
        const int k = i >> 10, n = i & 1023;
        w1T[(size_t)n * 256 + k] = f2b(w1[i]);
        return;
    }
    i -= 262144;
    if (i < 262144) {                                 // w2 [1024][256] -> [256][1024]
        const int k = i >> 8, n = i & 255;
        w2T[(size_t)n * 1024 + k] = f2b(w2[i]);
        return;
    }
    i -= 262144;
    if (i < 49152) {                                  // [w_off|w_attn|0] -> [384][128]
        const int nn = i >> 7, k = i & 127;
        float v = 0.f;
        if (nn < 192)      v = w_off[(size_t)k * 192 + nn];
        else if (nn < 288) v = w_attn[(size_t)k * 96 + (nn - 192)];
        wcT[i] = f2b(v);
        return;
    }
    i -= 49152;
    if (i < 384) {
        float b = 0.f;
        if (i < 192)      b = b_off[i];
        else if (i < 288) b = b_attn[i - 192];
        biasc[i] = b;
    }
}

// ---------------------------------------------------------------------------
extern "C" void kernel_launch(void* const* d_in, const int* in_sizes, int n_in,
                              void* d_out, int out_size, void* d_ws, size_t ws_size,
                              hipStream_t stream)
{
    const float* src     = (const float*)d_in[0];
    const float* flow    = (const float*)d_in[1];
    const float* w_value = (const float*)d_in[4];
    const float* b_value = (const float*)d_in[5];
    const float* w_off   = (const float*)d_in[6];
    const float* b_off   = (const float*)d_in[7];
    const float* w_attn  = (const float*)d_in[8];
    const float* b_attn  = (const float*)d_in[9];
    const float* w_out   = (const float*)d_in[10];
    const float* b_out   = (const float*)d_in[11];
    const float* gamma   = (const float*)d_in[12];
    const float* beta    = (const float*)d_in[13];
    const float* w1      = (const float*)d_in[14];
    const float* b1      = (const float*)d_in[15];
    const float* w2      = (const float*)d_in[16];
    const float* b2      = (const float*)d_in[17];
    float* out = (float*)d_out;
    char*  wsb = (char*)d_ws;

    // Workspace (bytes), lifetime-aliased; total ~93.7 MB:
    //   [0, 67108864)           ffn1_bf; earlier: value_bf [0,22MB) + acc_bf [22,39MB)
    //   [67108864, 92274688)    projc_bf (dead after sampler) -> ln_bf
    //   [92274688, ...)         bf16 weights + proj bias
    ushort* ffn1_bf  = (ushort*)(wsb);
    ushort* value_bf = (ushort*)(wsb);
    ushort* acc_bf   = (ushort*)(wsb + 22020096);
    ushort* projc_bf = (ushort*)(wsb + 67108864);
    ushort* ln_bf    = (ushort*)(wsb + 67108864);
    ushort* wvT      = (ushort*)(wsb + 92274688);
    ushort* woT      = (ushort*)(wsb + 92405760);
    ushort* w1T      = (ushort*)(wsb + 92536832);
    ushort* w2T      = (ushort*)(wsb + 93061120);
    ushort* wcT      = (ushort*)(wsb + 93585408);
    float*  biasc    = (float*) (wsb + 93683712);

    const int Mq = NB * LQ;     // 32768
    const int Mv = NB * LENIN;  // 43008

    // 0. all weight prep, one launch
    prep_all_k<<<2754, 256, 0, stream>>>(w_value, w_out, w1, w2,
                                         w_off, b_off, w_attn, b_attn,
                                         wvT, woT, w1T, w2T, wcT, biasc);

    // 1. value = src @ w_value + b_value  [43008 x 256] (fp32 A staged) bf16 out
    mfma_gemm<true, false, false, true><<<dim3(2, Mv / 128), 256, 0, stream>>>(
        src, wvT, b_value, nullptr, value_bf, 256, 256);

    // 2. proj = flow @ [w_off|w_attn|0] + bias  [32768 x 384] (fp32 A) bf16 out
    mfma_gemm<true, false, false, true><<<dim3(3, Mq / 128), 256, 0, stream>>>(
        flow, wcT, biasc, nullptr, projc_bf, 384, 128);

    // 3. deformable sampling (fused softmax)  [32768 x 256] bf16 out
    sample_k<<<Mq / 8, 256, 0, stream>>>(value_bf, projc_bf, acc_bf);

    // 4. x = acc @ w_out + b_out -> d_out fp32; ln = LN(x) -> bf16 (fused)
    gemm_ln_k<<<Mq / 64, 256, 0, stream>>>(
        acc_bf, woT, b_out, gamma, beta, out, ln_bf, 256);

    // 5. ffn1 = relu(ln @ w1 + b1) -> bf16  [32768 x 1024]
    mfma_gemm<false, true, false, true><<<dim3(8, Mq / 128), 256, 0, stream>>>(
        ln_bf, w1T, b1, nullptr, ffn1_bf, 1024, 256);

    // 6. out = x + ffn1 @ w2 + b2  [32768 x 256]
    mfma_gemm<false, false, true, false><<<dim3(2, Mq / 128), 256, 0, stream>>>(
        ffn1_bf, w2T, b2, out, out, 256, 1024);
}